// Round 2
// baseline (12012.792 us; speedup 1.0000x reference)
//
#include <hip/hip_runtime.h>
#include <hip/hip_bf16.h>
#include <math.h>

#define DEVINL __device__ __forceinline__

constexpr int L = 4, D = 512, FF = 2048, NH = 8, DH = 64, B = 8, S = 512;
constexpr int NN = 50000, EE = 800000, HG = 256, FUS = 768;
constexpr int T = B * S;   // 4096 tokens

DEVINL float waveRed(float v) { for (int o = 32; o; o >>= 1) v += __shfl_down(v, o); return v; }

// ---------------- K1: embedding + sinusoidal PE -> h (f32) ----------------
__global__ __launch_bounds__(256) void embed_kernel(const float* __restrict__ tok,
                                                    const int* __restrict__ ids, float* __restrict__ h) {
    int t = blockIdx.x;            // token index 0..4095
    int s = t & (S - 1);
    int id = ids[t];
    const float scale = 22.62741699796952f;               // sqrt(512)
    const float kln = 9.210340371976184f / 512.0f;        // ln(10000)/D
    for (int d = threadIdx.x; d < D; d += 256) {
        float e = tok[(size_t)id * D + d] * scale;
        float ang = (float)s * expf(-(float)(2 * (d >> 1)) * kln);
        float pe = (d & 1) ? cosf(ang) : sinf(ang);
        h[(size_t)t * D + d] = e + pe;
    }
}

// ---------------- K2: LayerNorm over D=512, block=256, one token/block ----------------
__global__ __launch_bounds__(256) void ln512_kernel(const float* __restrict__ in,
                                                    const float* __restrict__ w,
                                                    const float* __restrict__ bb,
                                                    float* __restrict__ out) {
    int t = blockIdx.x, tid = threadIdx.x;
    const float* row = in + (size_t)t * 512;
    float v0 = row[tid], v1 = row[tid + 256];
    float s1 = waveRed(v0 + v1);
    float s2 = waveRed(v0 * v0 + v1 * v1);
    __shared__ float p1[4], p2[4];
    if ((tid & 63) == 0) { p1[tid >> 6] = s1; p2[tid >> 6] = s2; }
    __syncthreads();
    float S1 = p1[0] + p1[1] + p1[2] + p1[3];
    float S2 = p2[0] + p2[1] + p2[2] + p2[3];
    float mu = S1 / 512.0f, var = S2 / 512.0f - mu * mu;
    float rs = rsqrtf(fmaxf(var, 0.0f) + 1e-5f);
    out[(size_t)t * 512 + tid]       = (v0 - mu) * rs * w[tid]       + bb[tid];
    out[(size_t)t * 512 + tid + 256] = (v1 - mu) * rs * w[tid + 256] + bb[tid + 256];
}

// ---------------- K3: tiled GEMM  C[M,N] = act(A[M,K] @ W[N,K]^T + bias (+res)) ----------------
// BM=BN=64, BK=16, 256 threads, 4x4 outputs/thread. M%64==0, N%64==0, K%16==0 assumed.
template <int ACT, bool RES>
__global__ __launch_bounds__(256) void gemm_kernel(const float* __restrict__ A,
                                                   const float* __restrict__ W,
                                                   const float* __restrict__ bias,
                                                   const float* __restrict__ res,
                                                   float* __restrict__ C, int M, int Nn, int K) {
    __shared__ float As[64][17];
    __shared__ float Ws[64][17];
    int bm = blockIdx.y * 64, bn = blockIdx.x * 64;
    int tid = threadIdx.x, tx = tid & 15, ty = tid >> 4;
    float acc[4][4] = {};
    int lr = tid >> 2;              // row within tile for loads (0..63)
    int lc = (tid & 3) * 4;         // starting col (0,4,8,12)
    for (int k0 = 0; k0 < K; k0 += 16) {
        float4 av = *(const float4*)&A[(size_t)(bm + lr) * K + k0 + lc];
        As[lr][lc + 0] = av.x; As[lr][lc + 1] = av.y; As[lr][lc + 2] = av.z; As[lr][lc + 3] = av.w;
        float4 wv = *(const float4*)&W[(size_t)(bn + lr) * K + k0 + lc];
        Ws[lr][lc + 0] = wv.x; Ws[lr][lc + 1] = wv.y; Ws[lr][lc + 2] = wv.z; Ws[lr][lc + 3] = wv.w;
        __syncthreads();
#pragma unroll
        for (int kk = 0; kk < 16; kk++) {
            float a[4], b[4];
#pragma unroll
            for (int i = 0; i < 4; i++) { a[i] = As[ty + 16 * i][kk]; b[i] = Ws[tx + 16 * i][kk]; }
#pragma unroll
            for (int i = 0; i < 4; i++)
#pragma unroll
                for (int j = 0; j < 4; j++) acc[i][j] += a[i] * b[j];
        }
        __syncthreads();
    }
#pragma unroll
    for (int i = 0; i < 4; i++) {
        int m = bm + ty + 16 * i;
#pragma unroll
        for (int j = 0; j < 4; j++) {
            int n = bn + tx + 16 * j;
            float v = acc[i][j] + bias[n];
            if (RES) v += res[(size_t)m * Nn + n];
            if (ACT == 1) v = 0.5f * v * (1.0f + erff(v * 0.70710678118654752f));  // exact GELU
            C[(size_t)m * Nn + n] = v;
        }
    }
}

// ---------------- K4: fused attention, 8 queries per block ----------------
__global__ __launch_bounds__(256) void attn_kernel(const float* __restrict__ qkv, float* __restrict__ o) {
    int blk = blockIdx.x;            // B*NH*(S/8) = 4096
    int qt = blk & 63;
    int h = (blk >> 6) & 7;
    int b = blk >> 9;
    int q0 = qt * 8;
    int tid = threadIdx.x;
    __shared__ float qv[8][64];
    __shared__ float sc[8][512];
    __shared__ float red[256];
    __shared__ float rowsum[8];
    for (int i = tid; i < 512; i += 256) {
        int q = i >> 6, d = i & 63;
        qv[q][d] = qkv[(size_t)(b * S + q0 + q) * (3 * D) + h * 64 + d];
    }
    __syncthreads();
    for (int k = tid; k < 512; k += 256) {
        const float4* kp4 = (const float4*)&qkv[(size_t)(b * S + k) * (3 * D) + D + h * 64];
        float acc[8] = {};
#pragma unroll 4
        for (int d4 = 0; d4 < 16; d4++) {
            float4 kv = kp4[d4];
#pragma unroll
            for (int q = 0; q < 8; q++) {
                float4 qq = *(const float4*)&qv[q][4 * d4];
                acc[q] += qq.x * kv.x + qq.y * kv.y + qq.z * kv.z + qq.w * kv.w;
            }
        }
#pragma unroll
        for (int q = 0; q < 8; q++) sc[q][k] = acc[q] * 0.125f;
    }
    __syncthreads();
    int q = tid >> 5, l = tid & 31;
    float m = -1e30f;
    for (int k = l; k < 512; k += 32) m = fmaxf(m, sc[q][k]);
    red[tid] = m; __syncthreads();
    for (int off = 16; off; off >>= 1) { if (l < off) red[tid] = fmaxf(red[tid], red[tid + off]); __syncthreads(); }
    float mx = red[q * 32];
    float ssum = 0.0f;
    for (int k = l; k < 512; k += 32) { float p = expf(sc[q][k] - mx); sc[q][k] = p; ssum += p; }
    __syncthreads();
    red[tid] = ssum; __syncthreads();
    for (int off = 16; off; off >>= 1) { if (l < off) red[tid] += red[tid + off]; __syncthreads(); }
    if (l == 0) rowsum[q] = red[q * 32];
    __syncthreads();
    int d = tid & 63, g2 = tid >> 6;
    int qa = g2 * 2, qb = qa + 1;
    float a0 = 0.0f, a1 = 0.0f;
    for (int k = 0; k < 512; k++) {
        float vv = qkv[(size_t)(b * S + k) * (3 * D) + 2 * D + h * 64 + d];
        a0 += sc[qa][k] * vv;
        a1 += sc[qb][k] * vv;
    }
    o[(size_t)(b * S + q0 + qa) * D + h * 64 + d] = a0 / rowsum[qa];
    o[(size_t)(b * S + q0 + qb) * D + h * 64 + d] = a1 / rowsum[qb];
}

// ---------------- K5: masked mean pool over S (mask all-true) ----------------
__global__ __launch_bounds__(256) void logpool_kernel(const float* __restrict__ hf, float* __restrict__ lp) {
    int idx = blockIdx.x * 256 + threadIdx.x;   // 0..4095 -> (b,d)
    int b = idx >> 9, d = idx & 511;
    float s = 0.0f;
    for (int t = 0; t < 512; t++) s += hf[(size_t)(b * 512 + t) * 512 + d];
    lp[idx] = s * (1.0f / 512.0f);
}

// ---------------- K6: node encoder: clip -> shared LN -> per-type affine+linear ----------------
__global__ __launch_bounds__(256) void node_enc_kernel(const float* __restrict__ x,
                                                       const int* __restrict__ ntype,
                                                       const float* __restrict__ glnw,
                                                       const float* __restrict__ glnb,
                                                       const float* __restrict__ gw,
                                                       const float* __restrict__ gb,
                                                       const float* __restrict__ temb,
                                                       float* __restrict__ g) {
    int n = blockIdx.x, tid = threadIdx.x;
    int t = ntype[n];
    __shared__ float xa[64];
    __shared__ float stat[2];
    float v = 0.0f;
    if (tid < 64) {
        v = x[(size_t)n * 64 + tid];
        v = fminf(10.0f, fmaxf(-10.0f, v));
        float s1 = waveRed(v);
        float s2 = waveRed(v * v);
        if (tid == 0) { stat[0] = s1; stat[1] = s2; }
    }
    __syncthreads();
    if (tid < 64) {
        float mu = stat[0] / 64.0f;
        float var = stat[1] / 64.0f - mu * mu;
        float rs = rsqrtf(fmaxf(var, 0.0f) + 1e-5f);
        xa[tid] = (v - mu) * rs * glnw[t * 64 + tid] + glnb[t * 64 + tid];
    }
    __syncthreads();
    const float4* w4 = (const float4*)(gw + ((size_t)t * 256 + tid) * 64);
    float acc = 0.0f;
#pragma unroll 4
    for (int f4 = 0; f4 < 16; f4++) {
        float4 u = w4[f4];
        acc += xa[4 * f4 + 0] * u.x + xa[4 * f4 + 1] * u.y
             + xa[4 * f4 + 2] * u.z + xa[4 * f4 + 3] * u.w;
    }
    g[(size_t)n * 256 + tid] = acc + gb[t * 256 + tid] + temb[t * 256 + tid];
}

// ---------------- K7: degree histogram ----------------
__global__ __launch_bounds__(256) void deg_kernel(const int* __restrict__ dst, float* __restrict__ deg) {
    int e = blockIdx.x * 256 + threadIdx.x;
    if (e < EE) atomicAdd(&deg[dst[e]], 1.0f);
}

// ---------------- K8: scatter-sum of g[src] into agg[dst] (4 channels/thread) ----------------
__global__ __launch_bounds__(256) void scatter_kernel(const float* __restrict__ g,
                                                      const int* __restrict__ src,
                                                      const int* __restrict__ dst,
                                                      float* __restrict__ agg) {
    long long id = (long long)blockIdx.x * 256 + threadIdx.x;   // EE*64 items
    int e = (int)(id >> 6);
    int c4 = ((int)id & 63) << 2;
    int sN = src[e], dN = dst[e];
    float4 v = *(const float4*)&g[(size_t)sN * 256 + c4];
    float* ap = &agg[(size_t)dN * 256 + c4];
    atomicAdd(ap + 0, v.x); atomicAdd(ap + 1, v.y);
    atomicAdd(ap + 2, v.z); atomicAdd(ap + 3, v.w);
}

// ---------------- K9: fused SAGE linear + residual + LN + ReLU (4 nodes/block, in-place on g) ----------------
__global__ __launch_bounds__(256) void sage_kernel(float* __restrict__ g,
                                                   const float* __restrict__ agg,
                                                   const float* __restrict__ deg,
                                                   const float* __restrict__ wl,
                                                   const float* __restrict__ bl,
                                                   const float* __restrict__ wr,
                                                   const float* __restrict__ gnw,
                                                   const float* __restrict__ gnb) {
    int n0 = blockIdx.x * 4;
    int tid = threadIdx.x;
    __shared__ float ar[4][256], gr[4][256];
    __shared__ float part[2][4][4];
#pragma unroll
    for (int i = 0; i < 4; i++) {
        int n = n0 + i;
        float den = fmaxf(deg[n], 1.0f);
        ar[i][tid] = agg[(size_t)n * 256 + tid] / den;
        gr[i][tid] = g[(size_t)n * 256 + tid];
    }
    __syncthreads();
    float bv = bl[tid];
    float acc[4] = { bv, bv, bv, bv };
    const float4* wl4 = (const float4*)(wl + (size_t)tid * 256);
    const float4* wr4 = (const float4*)(wr + (size_t)tid * 256);
#pragma unroll 2
    for (int f4 = 0; f4 < 64; f4++) {
        float4 uw = wl4[f4], ur = wr4[f4];
#pragma unroll
        for (int i = 0; i < 4; i++) {
            float4 av = *(const float4*)&ar[i][4 * f4];
            float4 gv = *(const float4*)&gr[i][4 * f4];
            acc[i] += av.x * uw.x + av.y * uw.y + av.z * uw.z + av.w * uw.w
                    + gv.x * ur.x + gv.y * ur.y + gv.z * ur.z + gv.w * ur.w;
        }
    }
    float v[4];
#pragma unroll
    for (int i = 0; i < 4; i++) v[i] = acc[i] + gr[i][tid];
    int wv = tid >> 6, ln = tid & 63;
#pragma unroll
    for (int i = 0; i < 4; i++) {
        float s1 = waveRed(v[i]);
        float s2 = waveRed(v[i] * v[i]);
        if (ln == 0) { part[0][i][wv] = s1; part[1][i][wv] = s2; }
    }
    __syncthreads();
    float gwv = gnw[tid], gbv = gnb[tid];
#pragma unroll
    for (int i = 0; i < 4; i++) {
        float S1 = part[0][i][0] + part[0][i][1] + part[0][i][2] + part[0][i][3];
        float S2 = part[1][i][0] + part[1][i][1] + part[1][i][2] + part[1][i][3];
        float mu = S1 / 256.0f, var = S2 / 256.0f - mu * mu;
        float rs = rsqrtf(fmaxf(var, 0.0f) + 1e-5f);
        float r = (v[i] - mu) * rs * gwv + gbv;
        g[(size_t)(n0 + i) * 256 + tid] = fmaxf(r, 0.0f);
    }
}

// ---------------- K11: column mean over N nodes ----------------
__global__ __launch_bounds__(256) void gpool_kernel(const float* __restrict__ g, float* __restrict__ psum) {
    int tid = threadIdx.x, blk = blockIdx.x;
    float acc = 0.0f;
    for (int n = blk; n < NN; n += 256) acc += g[(size_t)n * 256 + tid];
    atomicAdd(&psum[tid], acc);
}

// ---------------- K12: fusion linear + LN + ReLU -> f32 out ----------------
__global__ __launch_bounds__(256) void fusion_kernel(const float* __restrict__ lp,
                                                     const float* __restrict__ psum,
                                                     const float* __restrict__ fw,
                                                     const float* __restrict__ fb,
                                                     const float* __restrict__ flnw,
                                                     const float* __restrict__ flnb,
                                                     float* __restrict__ out) {
    int b = blockIdx.x, tid = threadIdx.x;
    __shared__ float fin[768], fo[768];
    __shared__ float p1[4], p2[4];
    for (int i = tid; i < 512; i += 256) fin[i] = lp[b * 512 + i];
    if (tid < 256) fin[512 + tid] = psum[tid] * (1.0f / 50000.0f);
    __syncthreads();
    for (int j = tid; j < 768; j += 256) {
        float acc = fb[j];
        const float4* w4 = (const float4*)(fw + (size_t)j * 768);
#pragma unroll 4
        for (int i4 = 0; i4 < 192; i4++) {
            float4 u = w4[i4];
            acc += fin[4 * i4 + 0] * u.x + fin[4 * i4 + 1] * u.y
                 + fin[4 * i4 + 2] * u.z + fin[4 * i4 + 3] * u.w;
        }
        fo[j] = acc;
    }
    __syncthreads();
    float s1 = 0.0f, s2 = 0.0f;
    for (int j = tid; j < 768; j += 256) { float vv = fo[j]; s1 += vv; s2 += vv * vv; }
    s1 = waveRed(s1); s2 = waveRed(s2);
    if ((tid & 63) == 0) { p1[tid >> 6] = s1; p2[tid >> 6] = s2; }
    __syncthreads();
    float S1 = p1[0] + p1[1] + p1[2] + p1[3];
    float S2 = p2[0] + p2[1] + p2[2] + p2[3];
    float mu = S1 / 768.0f, var = S2 / 768.0f - mu * mu;
    float rs = rsqrtf(fmaxf(var, 0.0f) + 1e-5f);
    for (int j = tid; j < 768; j += 256) {
        float r = (fo[j] - mu) * rs * flnw[j] + flnb[j];
        out[b * 768 + j] = fmaxf(r, 0.0f);
    }
}

extern "C" void kernel_launch(void* const* d_in, const int* in_sizes, int n_in,
                              void* d_out, int out_size, void* d_ws, size_t ws_size,
                              hipStream_t stream) {
    (void)in_sizes; (void)n_in; (void)out_size; (void)ws_size;
    const float* tok_emb = (const float*)d_in[0];
    const float* qkv_w   = (const float*)d_in[1];
    const float* qkv_b   = (const float*)d_in[2];
    const float* out_w   = (const float*)d_in[3];
    const float* out_b   = (const float*)d_in[4];
    const float* ln1_w   = (const float*)d_in[5];
    const float* ln1_b   = (const float*)d_in[6];
    const float* ln2_w   = (const float*)d_in[7];
    const float* ln2_b   = (const float*)d_in[8];
    const float* ff1_w   = (const float*)d_in[9];
    const float* ff1_b   = (const float*)d_in[10];
    const float* ff2_w   = (const float*)d_in[11];
    const float* ff2_b   = (const float*)d_in[12];
    const float* fln_w   = (const float*)d_in[13];
    const float* fln_b   = (const float*)d_in[14];
    const float* x       = (const float*)d_in[15];
    const float* gln_w   = (const float*)d_in[16];
    const float* gln_b   = (const float*)d_in[17];
    const float* gw      = (const float*)d_in[18];
    const float* gb      = (const float*)d_in[19];
    const float* temb    = (const float*)d_in[20];
    const float* sage_wl = (const float*)d_in[21];
    const float* sage_bl = (const float*)d_in[22];
    const float* sage_wr = (const float*)d_in[23];
    const float* gnorm_w = (const float*)d_in[24];
    const float* gnorm_b = (const float*)d_in[25];
    const float* fusion_w   = (const float*)d_in[26];
    const float* fusion_b   = (const float*)d_in[27];
    const float* fusion_lnw = (const float*)d_in[28];
    const float* fusion_lnb = (const float*)d_in[29];
    const int* input_ids  = (const int*)d_in[30];
    // d_in[31] = attention_mask: all-true by construction, unused
    const int* edge_index = (const int*)d_in[32];
    const int* node_type  = (const int*)d_in[33];
    const int* e_src = edge_index;
    const int* e_dst = edge_index + EE;

    // workspace layout (floats), total 25,654,352 floats = 102.6 MB
    float* ws  = (float*)d_ws;
    float* h   = ws;                      // [0, 2,097,152)
    float* y   = ws + 2097152;            // [2,097,152, 4,194,304)
    float* qkv = ws + 4194304;            // 6,291,456 floats (within big region)
    float* ff  = ws + 4194304;            // 8,388,608 floats; aliases qkv (dead after attn)
    float* g   = ws;                      // [0, 12,800,000)  aliases transformer scratch
    float* agg = ws + 12800000;           // [12.8M, 25.6M)
    float* deg = ws + 25600000;           // 50,000
    float* lp  = ws + 25650000;           // 4,096
    float* psum = ws + 25654096;          // 256

    // ---- transformer ----
    embed_kernel<<<T, 256, 0, stream>>>(tok_emb, input_ids, h);
    for (int l = 0; l < L; l++) {
        ln512_kernel<<<T, 256, 0, stream>>>(h, ln1_w + l * D, ln1_b + l * D, y);
        gemm_kernel<0, false><<<dim3(3 * D / 64, T / 64), 256, 0, stream>>>(
            y, qkv_w + (size_t)l * 3 * D * D, qkv_b + (size_t)l * 3 * D, nullptr, qkv, T, 3 * D, D);
        attn_kernel<<<B * NH * (S / 8), 256, 0, stream>>>(qkv, y);   // o -> y
        gemm_kernel<0, true><<<dim3(D / 64, T / 64), 256, 0, stream>>>(
            y, out_w + (size_t)l * D * D, out_b + (size_t)l * D, h, h, T, D, D);
        ln512_kernel<<<T, 256, 0, stream>>>(h, ln2_w + l * D, ln2_b + l * D, y);
        gemm_kernel<1, false><<<dim3(FF / 64, T / 64), 256, 0, stream>>>(
            y, ff1_w + (size_t)l * FF * D, ff1_b + (size_t)l * FF, nullptr, ff, T, FF, D);
        gemm_kernel<0, true><<<dim3(D / 64, T / 64), 256, 0, stream>>>(
            ff, ff2_w + (size_t)l * D * FF, ff2_b + (size_t)l * D, h, h, T, D, FF);
    }
    ln512_kernel<<<T, 256, 0, stream>>>(h, fln_w, fln_b, y);
    logpool_kernel<<<(B * D) / 256, 256, 0, stream>>>(y, lp);

    // ---- graph ----  (g overwrites transformer scratch; lp lives beyond agg)
    node_enc_kernel<<<NN, 256, 0, stream>>>(x, node_type, gln_w, gln_b, gw, gb, temb, g);
    hipMemsetAsync(deg, 0, NN * sizeof(float), stream);
    deg_kernel<<<(EE + 255) / 256, 256, 0, stream>>>(e_dst, deg);
    for (int l = 0; l < 2; l++) {
        hipMemsetAsync(agg, 0, (size_t)NN * HG * sizeof(float), stream);
        scatter_kernel<<<(int)(((long long)EE * 64) / 256), 256, 0, stream>>>(g, e_src, e_dst, agg);
        sage_kernel<<<NN / 4, 256, 0, stream>>>(g, agg, deg,
            sage_wl + (size_t)l * HG * HG, sage_bl + (size_t)l * HG, sage_wr + (size_t)l * HG * HG,
            gnorm_w + (size_t)l * HG, gnorm_b + (size_t)l * HG);
    }
    hipMemsetAsync(psum, 0, HG * sizeof(float), stream);
    gpool_kernel<<<256, 256, 0, stream>>>(g, psum);
    fusion_kernel<<<B, 256, 0, stream>>>(lp, psum, fusion_w, fusion_b, fusion_lnw, fusion_lnb,
                                         (float*)d_out);
}

// Round 3
// 5398.078 us; speedup vs baseline: 2.2254x; 2.2254x over previous
//
#include <hip/hip_runtime.h>
#include <hip/hip_bf16.h>
#include <math.h>

#define DEVINL __device__ __forceinline__

constexpr int L = 4, D = 512, FF = 2048, NH = 8, DH = 64, B = 8, S = 512;
constexpr int NN = 50000, EE = 800000, HG = 256, FUS = 768;
constexpr int T = B * S;   // 4096 tokens

typedef __attribute__((ext_vector_type(8))) short short8;
typedef __attribute__((ext_vector_type(8))) unsigned short ushort8;
typedef __attribute__((ext_vector_type(4))) float floatx4;

DEVINL float waveRed(float v) { for (int o = 32; o; o >>= 1) v += __shfl_down(v, o); return v; }

DEVINL unsigned short f2bf(float f) {
    union { float f; unsigned int u; } c; c.f = f;
    unsigned int r = c.u + 0x7fffu + ((c.u >> 16) & 1u);   // RNE
    return (unsigned short)(r >> 16);
}
DEVINL ushort8 pack8(floatx4 x, floatx4 y) {
    ushort8 r;
    r[0] = f2bf(x[0]); r[1] = f2bf(x[1]); r[2] = f2bf(x[2]); r[3] = f2bf(x[3]);
    r[4] = f2bf(y[0]); r[5] = f2bf(y[1]); r[6] = f2bf(y[2]); r[7] = f2bf(y[3]);
    return r;
}

// ---------------- K1: embedding + sinusoidal PE -> h (f32) ----------------
__global__ __launch_bounds__(256) void embed_kernel(const float* __restrict__ tok,
                                                    const int* __restrict__ ids, float* __restrict__ h) {
    int t = blockIdx.x;
    int s = t & (S - 1);
    int id = ids[t];
    const float scale = 22.62741699796952f;               // sqrt(512)
    const float kln = 9.210340371976184f / 512.0f;        // ln(10000)/D
    for (int d = threadIdx.x; d < D; d += 256) {
        float e = tok[(size_t)id * D + d] * scale;
        float ang = (float)s * expf(-(float)(2 * (d >> 1)) * kln);
        float pe = (d & 1) ? cosf(ang) : sinf(ang);
        h[(size_t)t * D + d] = e + pe;
    }
}

// ---------------- K2: LayerNorm over D=512 ----------------
__global__ __launch_bounds__(256) void ln512_kernel(const float* __restrict__ in,
                                                    const float* __restrict__ w,
                                                    const float* __restrict__ bb,
                                                    float* __restrict__ out) {
    int t = blockIdx.x, tid = threadIdx.x;
    const float* row = in + (size_t)t * 512;
    float v0 = row[tid], v1 = row[tid + 256];
    float s1 = waveRed(v0 + v1);
    float s2 = waveRed(v0 * v0 + v1 * v1);
    __shared__ float p1[4], p2[4];
    if ((tid & 63) == 0) { p1[tid >> 6] = s1; p2[tid >> 6] = s2; }
    __syncthreads();
    float S1 = p1[0] + p1[1] + p1[2] + p1[3];
    float S2 = p2[0] + p2[1] + p2[2] + p2[3];
    float mu = S1 / 512.0f, var = S2 / 512.0f - mu * mu;
    float rs = rsqrtf(fmaxf(var, 0.0f) + 1e-5f);
    out[(size_t)t * 512 + tid]       = (v0 - mu) * rs * w[tid]       + bb[tid];
    out[(size_t)t * 512 + tid + 256] = (v1 - mu) * rs * w[tid + 256] + bb[tid + 256];
}

// ---------------- K3: bf16 MFMA GEMM  C[M,N] = act(A[M,K] @ W[N,K]^T + bias (+res)) ----------------
// 128x128 tile, BK=32, 256 threads = 4 waves in 2x2; each wave: 4x4 of 16x16x32 MFMA.
// f32 inputs converted to bf16 (RNE) during LDS staging; f32 accumulate.
template <int ACT, bool RES>
__global__ __launch_bounds__(256) void mfma_gemm_kernel(const float* __restrict__ A,
                                                        const float* __restrict__ W,
                                                        const float* __restrict__ bias,
                                                        const float* __restrict__ res,
                                                        float* __restrict__ C, int M, int Nn, int K) {
    constexpr int LDH = 40;                      // halfwords/row: 32 + 8 pad (80 B, 16B-aligned)
    __shared__ unsigned short As[128 * LDH];
    __shared__ unsigned short Ws[128 * LDH];
    const int bm = blockIdx.y * 128, bn = blockIdx.x * 128;
    const int tid = threadIdx.x;
    const int lane = tid & 63, wave = tid >> 6;
    const int wm = (wave & 1) * 64, wn = (wave >> 1) * 64;
    const int fr = lane & 15, fq = lane >> 4;    // fragment row / quad
    floatx4 acc[4][4] = {};
    const int srow = tid >> 1, shalf = (tid & 1) * 16;
    const float* aG = &A[(size_t)(bm + srow) * K + shalf];
    const float* wG = &W[(size_t)(bn + srow) * K + shalf];
    unsigned short* aS = &As[srow * LDH + shalf];
    unsigned short* wS = &Ws[srow * LDH + shalf];
    for (int k0 = 0; k0 < K; k0 += 32) {
        floatx4 a0 = *(const floatx4*)(aG + k0);
        floatx4 a1 = *(const floatx4*)(aG + k0 + 4);
        floatx4 a2 = *(const floatx4*)(aG + k0 + 8);
        floatx4 a3 = *(const floatx4*)(aG + k0 + 12);
        floatx4 w0 = *(const floatx4*)(wG + k0);
        floatx4 w1 = *(const floatx4*)(wG + k0 + 4);
        floatx4 w2 = *(const floatx4*)(wG + k0 + 8);
        floatx4 w3 = *(const floatx4*)(wG + k0 + 12);
        __syncthreads();                          // previous iter's frag reads done
        *(ushort8*)(aS)     = pack8(a0, a1);
        *(ushort8*)(aS + 8) = pack8(a2, a3);
        *(ushort8*)(wS)     = pack8(w0, w1);
        *(ushort8*)(wS + 8) = pack8(w2, w3);
        __syncthreads();
        short8 af[4], bfr[4];
#pragma unroll
        for (int i = 0; i < 4; i++) {
            af[i]  = *(const short8*)&As[(wm + i * 16 + fr) * LDH + fq * 8];
            bfr[i] = *(const short8*)&Ws[(wn + i * 16 + fr) * LDH + fq * 8];
        }
#pragma unroll
        for (int mi = 0; mi < 4; mi++)
#pragma unroll
            for (int ni = 0; ni < 4; ni++)
                acc[mi][ni] = __builtin_amdgcn_mfma_f32_16x16x32_bf16(af[mi], bfr[ni], acc[mi][ni], 0, 0, 0);
    }
#pragma unroll
    for (int mi = 0; mi < 4; mi++) {
#pragma unroll
        for (int r = 0; r < 4; r++) {
            int row = bm + wm + mi * 16 + fq * 4 + r;
#pragma unroll
            for (int ni = 0; ni < 4; ni++) {
                int col = bn + wn + ni * 16 + fr;
                float v = acc[mi][ni][r] + bias[col];
                if (RES) v += res[(size_t)row * Nn + col];
                if (ACT == 1) v = 0.5f * v * (1.0f + erff(v * 0.70710678118654752f));
                C[(size_t)row * Nn + col] = v;
            }
        }
    }
}

// ---------------- K4: fused attention, 8 queries per block ----------------
__global__ __launch_bounds__(256) void attn_kernel(const float* __restrict__ qkv, float* __restrict__ o) {
    int blk = blockIdx.x;            // B*NH*(S/8) = 4096
    int qt = blk & 63;
    int h = (blk >> 6) & 7;
    int b = blk >> 9;
    int q0 = qt * 8;
    int tid = threadIdx.x;
    __shared__ float qv[8][64];
    __shared__ float sc[8][512];
    __shared__ float red[256];
    __shared__ float rowsum[8];
    for (int i = tid; i < 512; i += 256) {
        int q = i >> 6, d = i & 63;
        qv[q][d] = qkv[(size_t)(b * S + q0 + q) * (3 * D) + h * 64 + d];
    }
    __syncthreads();
    for (int k = tid; k < 512; k += 256) {
        const float4* kp4 = (const float4*)&qkv[(size_t)(b * S + k) * (3 * D) + D + h * 64];
        float acc[8] = {};
#pragma unroll 4
        for (int d4 = 0; d4 < 16; d4++) {
            float4 kv = kp4[d4];
#pragma unroll
            for (int q = 0; q < 8; q++) {
                float4 qq = *(const float4*)&qv[q][4 * d4];
                acc[q] += qq.x * kv.x + qq.y * kv.y + qq.z * kv.z + qq.w * kv.w;
            }
        }
#pragma unroll
        for (int q = 0; q < 8; q++) sc[q][k] = acc[q] * 0.125f;
    }
    __syncthreads();
    int q = tid >> 5, l = tid & 31;
    float m = -1e30f;
    for (int k = l; k < 512; k += 32) m = fmaxf(m, sc[q][k]);
    red[tid] = m; __syncthreads();
    for (int off = 16; off; off >>= 1) { if (l < off) red[tid] = fmaxf(red[tid], red[tid + off]); __syncthreads(); }
    float mx = red[q * 32];
    float ssum = 0.0f;
    for (int k = l; k < 512; k += 32) { float p = expf(sc[q][k] - mx); sc[q][k] = p; ssum += p; }
    __syncthreads();
    red[tid] = ssum; __syncthreads();
    for (int off = 16; off; off >>= 1) { if (l < off) red[tid] += red[tid + off]; __syncthreads(); }
    if (l == 0) rowsum[q] = red[q * 32];
    __syncthreads();
    int d = tid & 63, g2 = tid >> 6;
    int qa = g2 * 2, qb = qa + 1;
    float a0 = 0.0f, a1 = 0.0f;
    for (int k = 0; k < 512; k++) {
        float vv = qkv[(size_t)(b * S + k) * (3 * D) + 2 * D + h * 64 + d];
        a0 += sc[qa][k] * vv;
        a1 += sc[qb][k] * vv;
    }
    o[(size_t)(b * S + q0 + qa) * D + h * 64 + d] = a0 / rowsum[qa];
    o[(size_t)(b * S + q0 + qb) * D + h * 64 + d] = a1 / rowsum[qb];
}

// ---------------- K5: masked mean pool over S ----------------
__global__ __launch_bounds__(256) void logpool_kernel(const float* __restrict__ hf, float* __restrict__ lp) {
    int idx = blockIdx.x * 256 + threadIdx.x;
    int b = idx >> 9, d = idx & 511;
    float s = 0.0f;
    for (int t = 0; t < 512; t++) s += hf[(size_t)(b * 512 + t) * 512 + d];
    lp[idx] = s * (1.0f / 512.0f);
}

// ---------------- K6: node encoder ----------------
__global__ __launch_bounds__(256) void node_enc_kernel(const float* __restrict__ x,
                                                       const int* __restrict__ ntype,
                                                       const float* __restrict__ glnw,
                                                       const float* __restrict__ glnb,
                                                       const float* __restrict__ gw,
                                                       const float* __restrict__ gb,
                                                       const float* __restrict__ temb,
                                                       float* __restrict__ g) {
    int n = blockIdx.x, tid = threadIdx.x;
    int t = ntype[n];
    __shared__ float xa[64];
    __shared__ float stat[2];
    float v = 0.0f;
    if (tid < 64) {
        v = x[(size_t)n * 64 + tid];
        v = fminf(10.0f, fmaxf(-10.0f, v));
        float s1 = waveRed(v);
        float s2 = waveRed(v * v);
        if (tid == 0) { stat[0] = s1; stat[1] = s2; }
    }
    __syncthreads();
    if (tid < 64) {
        float mu = stat[0] / 64.0f;
        float var = stat[1] / 64.0f - mu * mu;
        float rs = rsqrtf(fmaxf(var, 0.0f) + 1e-5f);
        xa[tid] = (v - mu) * rs * glnw[t * 64 + tid] + glnb[t * 64 + tid];
    }
    __syncthreads();
    const float4* w4 = (const float4*)(gw + ((size_t)t * 256 + tid) * 64);
    float acc = 0.0f;
#pragma unroll 4
    for (int f4 = 0; f4 < 16; f4++) {
        float4 u = w4[f4];
        acc += xa[4 * f4 + 0] * u.x + xa[4 * f4 + 1] * u.y
             + xa[4 * f4 + 2] * u.z + xa[4 * f4 + 3] * u.w;
    }
    g[(size_t)n * 256 + tid] = acc + gb[t * 256 + tid] + temb[t * 256 + tid];
}

// ---------------- CSR build ----------------
__global__ __launch_bounds__(256) void hist_kernel(const int* __restrict__ dst, int* __restrict__ deg) {
    int e = blockIdx.x * 256 + threadIdx.x;
    if (e < EE) atomicAdd(&deg[dst[e]], 1);
}

// single block, 256 threads: exclusive scan of deg -> row_start[NN+1], cursor copy
__global__ __launch_bounds__(256) void scan_kernel(const int* __restrict__ deg,
                                                   int* __restrict__ row_start,
                                                   int* __restrict__ cursor) {
    constexpr int CH = (NN + 255) / 256;   // 196
    int tid = threadIdx.x;
    __shared__ int part[256];
    int begin = tid * CH;
    int sum = 0;
    for (int i = 0; i < CH; i++) { int idx = begin + i; if (idx < NN) sum += deg[idx]; }
    part[tid] = sum;
    __syncthreads();
    for (int off = 1; off < 256; off <<= 1) {
        int t = (tid >= off) ? part[tid - off] : 0;
        __syncthreads();
        part[tid] += t;
        __syncthreads();
    }
    int run = part[tid] - sum;             // exclusive offset
    for (int i = 0; i < CH; i++) {
        int idx = begin + i;
        if (idx < NN) {
            row_start[idx] = run; cursor[idx] = run;
            run += deg[idx];
        }
    }
    if (tid == 255) row_start[NN] = run;   // == EE
}

__global__ __launch_bounds__(256) void fill_kernel(const int* __restrict__ src,
                                                   const int* __restrict__ dst,
                                                   int* __restrict__ cursor,
                                                   int* __restrict__ csr_src) {
    int e = blockIdx.x * 256 + threadIdx.x;
    if (e < EE) {
        int pos = atomicAdd(&cursor[dst[e]], 1);
        csr_src[pos] = src[e];
    }
}

// ---------------- K8': gather-mean aggregation (one dst node per block) ----------------
__global__ __launch_bounds__(256) void gather_mean_kernel(const float* __restrict__ g,
                                                          const int* __restrict__ csr_src,
                                                          const int* __restrict__ row_start,
                                                          float* __restrict__ agg) {
    int n = blockIdx.x, tid = threadIdx.x;
    int beg = row_start[n], end = row_start[n + 1];
    float acc = 0.0f;
    for (int i = beg; i < end; i++) {
        int s = csr_src[i];
        acc += g[(size_t)s * 256 + tid];
    }
    float den = (end > beg) ? (float)(end - beg) : 1.0f;
    agg[(size_t)n * 256 + tid] = acc / den;
}

// ---------------- K9: fused SAGE linear + residual + LN + ReLU (agg already mean) ----------------
__global__ __launch_bounds__(256) void sage_kernel(float* __restrict__ g,
                                                   const float* __restrict__ agg,
                                                   const float* __restrict__ wl,
                                                   const float* __restrict__ bl,
                                                   const float* __restrict__ wr,
                                                   const float* __restrict__ gnw,
                                                   const float* __restrict__ gnb) {
    int n0 = blockIdx.x * 4;
    int tid = threadIdx.x;
    __shared__ float ar[4][256], gr[4][256];
    __shared__ float part[2][4][4];
#pragma unroll
    for (int i = 0; i < 4; i++) {
        int n = n0 + i;
        ar[i][tid] = agg[(size_t)n * 256 + tid];
        gr[i][tid] = g[(size_t)n * 256 + tid];
    }
    __syncthreads();
    float bv = bl[tid];
    float acc[4] = { bv, bv, bv, bv };
    const float4* wl4 = (const float4*)(wl + (size_t)tid * 256);
    const float4* wr4 = (const float4*)(wr + (size_t)tid * 256);
#pragma unroll 2
    for (int f4 = 0; f4 < 64; f4++) {
        float4 uw = wl4[f4], ur = wr4[f4];
#pragma unroll
        for (int i = 0; i < 4; i++) {
            float4 av = *(const float4*)&ar[i][4 * f4];
            float4 gv = *(const float4*)&gr[i][4 * f4];
            acc[i] += av.x * uw.x + av.y * uw.y + av.z * uw.z + av.w * uw.w
                    + gv.x * ur.x + gv.y * ur.y + gv.z * ur.z + gv.w * ur.w;
        }
    }
    float v[4];
#pragma unroll
    for (int i = 0; i < 4; i++) v[i] = acc[i] + gr[i][tid];
    int wv = tid >> 6, ln = tid & 63;
#pragma unroll
    for (int i = 0; i < 4; i++) {
        float s1 = waveRed(v[i]);
        float s2 = waveRed(v[i] * v[i]);
        if (ln == 0) { part[0][i][wv] = s1; part[1][i][wv] = s2; }
    }
    __syncthreads();
    float gwv = gnw[tid], gbv = gnb[tid];
#pragma unroll
    for (int i = 0; i < 4; i++) {
        float S1 = part[0][i][0] + part[0][i][1] + part[0][i][2] + part[0][i][3];
        float S2 = part[1][i][0] + part[1][i][1] + part[1][i][2] + part[1][i][3];
        float mu = S1 / 256.0f, var = S2 / 256.0f - mu * mu;
        float rs = rsqrtf(fmaxf(var, 0.0f) + 1e-5f);
        float r = (v[i] - mu) * rs * gwv + gbv;
        g[(size_t)(n0 + i) * 256 + tid] = fmaxf(r, 0.0f);
    }
}

// ---------------- K11: column mean over N nodes ----------------
__global__ __launch_bounds__(256) void gpool_kernel(const float* __restrict__ g, float* __restrict__ psum) {
    int tid = threadIdx.x, blk = blockIdx.x;
    float acc = 0.0f;
    for (int n = blk; n < NN; n += 256) acc += g[(size_t)n * 256 + tid];
    atomicAdd(&psum[tid], acc);
}

// ---------------- K12: fusion linear + LN + ReLU -> f32 out ----------------
__global__ __launch_bounds__(256) void fusion_kernel(const float* __restrict__ lp,
                                                     const float* __restrict__ psum,
                                                     const float* __restrict__ fw,
                                                     const float* __restrict__ fb,
                                                     const float* __restrict__ flnw,
                                                     const float* __restrict__ flnb,
                                                     float* __restrict__ out) {
    int b = blockIdx.x, tid = threadIdx.x;
    __shared__ float fin[768], fo[768];
    __shared__ float p1[4], p2[4];
    for (int i = tid; i < 512; i += 256) fin[i] = lp[b * 512 + i];
    if (tid < 256) fin[512 + tid] = psum[tid] * (1.0f / 50000.0f);
    __syncthreads();
    for (int j = tid; j < 768; j += 256) {
        float acc = fb[j];
        const float4* w4 = (const float4*)(fw + (size_t)j * 768);
#pragma unroll 4
        for (int i4 = 0; i4 < 192; i4++) {
            float4 u = w4[i4];
            acc += fin[4 * i4 + 0] * u.x + fin[4 * i4 + 1] * u.y
                 + fin[4 * i4 + 2] * u.z + fin[4 * i4 + 3] * u.w;
        }
        fo[j] = acc;
    }
    __syncthreads();
    float s1 = 0.0f, s2 = 0.0f;
    for (int j = tid; j < 768; j += 256) { float vv = fo[j]; s1 += vv; s2 += vv * vv; }
    s1 = waveRed(s1); s2 = waveRed(s2);
    if ((tid & 63) == 0) { p1[tid >> 6] = s1; p2[tid >> 6] = s2; }
    __syncthreads();
    float S1 = p1[0] + p1[1] + p1[2] + p1[3];
    float S2 = p2[0] + p2[1] + p2[2] + p2[3];
    float mu = S1 / 768.0f, var = S2 / 768.0f - mu * mu;
    float rs = rsqrtf(fmaxf(var, 0.0f) + 1e-5f);
    for (int j = tid; j < 768; j += 256) {
        float r = (fo[j] - mu) * rs * flnw[j] + flnb[j];
        out[b * 768 + j] = fmaxf(r, 0.0f);
    }
}

extern "C" void kernel_launch(void* const* d_in, const int* in_sizes, int n_in,
                              void* d_out, int out_size, void* d_ws, size_t ws_size,
                              hipStream_t stream) {
    (void)in_sizes; (void)n_in; (void)out_size; (void)ws_size;
    const float* tok_emb = (const float*)d_in[0];
    const float* qkv_w   = (const float*)d_in[1];
    const float* qkv_b   = (const float*)d_in[2];
    const float* out_w   = (const float*)d_in[3];
    const float* out_b   = (const float*)d_in[4];
    const float* ln1_w   = (const float*)d_in[5];
    const float* ln1_b   = (const float*)d_in[6];
    const float* ln2_w   = (const float*)d_in[7];
    const float* ln2_b   = (const float*)d_in[8];
    const float* ff1_w   = (const float*)d_in[9];
    const float* ff1_b   = (const float*)d_in[10];
    const float* ff2_w   = (const float*)d_in[11];
    const float* ff2_b   = (const float*)d_in[12];
    const float* fln_w   = (const float*)d_in[13];
    const float* fln_b   = (const float*)d_in[14];
    const float* x       = (const float*)d_in[15];
    const float* gln_w   = (const float*)d_in[16];
    const float* gln_b   = (const float*)d_in[17];
    const float* gw      = (const float*)d_in[18];
    const float* gb      = (const float*)d_in[19];
    const float* temb    = (const float*)d_in[20];
    const float* sage_wl = (const float*)d_in[21];
    const float* sage_bl = (const float*)d_in[22];
    const float* sage_wr = (const float*)d_in[23];
    const float* gnorm_w = (const float*)d_in[24];
    const float* gnorm_b = (const float*)d_in[25];
    const float* fusion_w   = (const float*)d_in[26];
    const float* fusion_b   = (const float*)d_in[27];
    const float* fusion_lnw = (const float*)d_in[28];
    const float* fusion_lnb = (const float*)d_in[29];
    const int* input_ids  = (const int*)d_in[30];
    // d_in[31] = attention_mask: all-true, unused
    const int* edge_index = (const int*)d_in[32];
    const int* node_type  = (const int*)d_in[33];
    const int* e_src = edge_index;
    const int* e_dst = edge_index + EE;

    // workspace layout (floats)
    float* ws  = (float*)d_ws;
    float* h   = ws;                      // [0, 2.1M)
    float* y   = ws + 2097152;            // [2.1M, 4.2M)
    float* qkv = ws + 4194304;            // 6.29M floats
    float* ff  = ws + 4194304;            // 8.39M floats (aliases qkv; qkv dead after attn)
    float* g   = ws;                      // [0, 12.8M)  aliases transformer scratch
    float* agg = ws + 12800000;           // [12.8M, 25.6M)
    float* lp  = ws + 25600000;           // 4096
    float* psum = ws + 25604096;          // 256
    int* ibase     = (int*)(ws + 25604352);
    int* deg_i     = ibase;               // 50,000
    int* row_start = ibase + 50000;       // 50,001
    int* cursor    = ibase + 100001;      // 50,000
    int* csr_src   = ibase + 150001;      // 800,000
    // total: 26,554,353 * 4 B = 106.2 MB

    // ---- transformer ----
    embed_kernel<<<T, 256, 0, stream>>>(tok_emb, input_ids, h);
    for (int l = 0; l < L; l++) {
        ln512_kernel<<<T, 256, 0, stream>>>(h, ln1_w + l * D, ln1_b + l * D, y);
        mfma_gemm_kernel<0, false><<<dim3(3 * D / 128, T / 128), 256, 0, stream>>>(
            y, qkv_w + (size_t)l * 3 * D * D, qkv_b + (size_t)l * 3 * D, nullptr, qkv, T, 3 * D, D);
        attn_kernel<<<B * NH * (S / 8), 256, 0, stream>>>(qkv, y);   // o -> y
        mfma_gemm_kernel<0, true><<<dim3(D / 128, T / 128), 256, 0, stream>>>(
            y, out_w + (size_t)l * D * D, out_b + (size_t)l * D, h, h, T, D, D);
        ln512_kernel<<<T, 256, 0, stream>>>(h, ln2_w + l * D, ln2_b + l * D, y);
        mfma_gemm_kernel<1, false><<<dim3(FF / 128, T / 128), 256, 0, stream>>>(
            y, ff1_w + (size_t)l * FF * D, ff1_b + (size_t)l * FF, nullptr, ff, T, FF, D);
        mfma_gemm_kernel<0, true><<<dim3(D / 128, T / 128), 256, 0, stream>>>(
            ff, ff2_w + (size_t)l * D * FF, ff2_b + (size_t)l * D, h, h, T, D, FF);
    }
    ln512_kernel<<<T, 256, 0, stream>>>(h, fln_w, fln_b, y);
    logpool_kernel<<<(B * D) / 256, 256, 0, stream>>>(y, lp);

    // ---- graph: node encode + CSR build + 2 SAGE layers ----
    node_enc_kernel<<<NN, 256, 0, stream>>>(x, node_type, gln_w, gln_b, gw, gb, temb, g);
    hipMemsetAsync(deg_i, 0, NN * sizeof(int), stream);
    hist_kernel<<<(EE + 255) / 256, 256, 0, stream>>>(e_dst, deg_i);
    scan_kernel<<<1, 256, 0, stream>>>(deg_i, row_start, cursor);
    fill_kernel<<<(EE + 255) / 256, 256, 0, stream>>>(e_src, e_dst, cursor, csr_src);
    for (int l = 0; l < 2; l++) {
        gather_mean_kernel<<<NN, 256, 0, stream>>>(g, csr_src, row_start, agg);
        sage_kernel<<<NN / 4, 256, 0, stream>>>(g, agg,
            sage_wl + (size_t)l * HG * HG, sage_bl + (size_t)l * HG, sage_wr + (size_t)l * HG * HG,
            gnorm_w + (size_t)l * HG, gnorm_b + (size_t)l * HG);
    }
    hipMemsetAsync(psum, 0, HG * sizeof(float), stream);
    gpool_kernel<<<256, 256, 0, stream>>>(g, psum);
    fusion_kernel<<<B, 256, 0, stream>>>(lp, psum, fusion_w, fusion_b, fusion_lnw, fusion_lnb,
                                         (float*)d_out);
}

// Round 4
// 3207.680 us; speedup vs baseline: 3.7450x; 1.6829x over previous
//
#include <hip/hip_runtime.h>
#include <hip/hip_bf16.h>
#include <math.h>

#define DEVINL __device__ __forceinline__

constexpr int L = 4, D = 512, FF = 2048, NH = 8, DH = 64, B = 8, S = 512;
constexpr int NN = 50000, EE = 800000, HG = 256, FUS = 768;
constexpr int T = B * S;   // 4096 tokens
constexpr int NPAD = 50048;  // 391 * 128

typedef __attribute__((ext_vector_type(8))) short short8;
typedef __attribute__((ext_vector_type(8))) unsigned short ushort8;
typedef __attribute__((ext_vector_type(4))) float floatx4;

DEVINL float waveRed(float v) { for (int o = 32; o; o >>= 1) v += __shfl_down(v, o); return v; }

DEVINL float ubf(unsigned short u) { union { unsigned int i; float f; } c; c.i = ((unsigned int)u) << 16; return c.f; }
DEVINL unsigned short f2bf(float f) {
    union { float f; unsigned int u; } c; c.f = f;
    unsigned int r = c.u + 0x7fffu + ((c.u >> 16) & 1u);   // RNE
    return (unsigned short)(r >> 16);
}
DEVINL ushort8 pack8(floatx4 x, floatx4 y) {
    ushort8 r;
    r[0] = f2bf(x[0]); r[1] = f2bf(x[1]); r[2] = f2bf(x[2]); r[3] = f2bf(x[3]);
    r[4] = f2bf(y[0]); r[5] = f2bf(y[1]); r[6] = f2bf(y[2]); r[7] = f2bf(y[3]);
    return r;
}

// ---------------- K1: embedding + sinusoidal PE -> h (f32) ----------------
__global__ __launch_bounds__(256) void embed_kernel(const float* __restrict__ tok,
                                                    const int* __restrict__ ids, float* __restrict__ h) {
    int t = blockIdx.x;
    int s = t & (S - 1);
    int id = ids[t];
    const float scale = 22.62741699796952f;               // sqrt(512)
    const float kln = 9.210340371976184f / 512.0f;        // ln(10000)/D
    for (int d = threadIdx.x; d < D; d += 256) {
        float e = tok[(size_t)id * D + d] * scale;
        float ang = (float)s * expf(-(float)(2 * (d >> 1)) * kln);
        float pe = (d & 1) ? cosf(ang) : sinf(ang);
        h[(size_t)t * D + d] = e + pe;
    }
}

// ---------------- K2: LayerNorm over D=512 ----------------
__global__ __launch_bounds__(256) void ln512_kernel(const float* __restrict__ in,
                                                    const float* __restrict__ w,
                                                    const float* __restrict__ bb,
                                                    float* __restrict__ out) {
    int t = blockIdx.x, tid = threadIdx.x;
    const float* row = in + (size_t)t * 512;
    float v0 = row[tid], v1 = row[tid + 256];
    float s1 = waveRed(v0 + v1);
    float s2 = waveRed(v0 * v0 + v1 * v1);
    __shared__ float p1[4], p2[4];
    if ((tid & 63) == 0) { p1[tid >> 6] = s1; p2[tid >> 6] = s2; }
    __syncthreads();
    float S1 = p1[0] + p1[1] + p1[2] + p1[3];
    float S2 = p2[0] + p2[1] + p2[2] + p2[3];
    float mu = S1 / 512.0f, var = S2 / 512.0f - mu * mu;
    float rs = rsqrtf(fmaxf(var, 0.0f) + 1e-5f);
    out[(size_t)t * 512 + tid]       = (v0 - mu) * rs * w[tid]       + bb[tid];
    out[(size_t)t * 512 + tid + 256] = (v1 - mu) * rs * w[tid + 256] + bb[tid + 256];
}

// ---------------- K3: bf16 MFMA GEMM  C[M,N] = act(A[M,K] @ W[N,K]^T + bias (+res)) ----------------
template <int ACT, bool RES>
__global__ __launch_bounds__(256) void mfma_gemm_kernel(const float* __restrict__ A,
                                                        const float* __restrict__ W,
                                                        const float* __restrict__ bias,
                                                        const float* __restrict__ res,
                                                        float* __restrict__ C, int M, int Nn, int K) {
    constexpr int LDH = 40;
    __shared__ unsigned short As[128 * LDH];
    __shared__ unsigned short Ws[128 * LDH];
    const int bm = blockIdx.y * 128, bn = blockIdx.x * 128;
    const int tid = threadIdx.x;
    const int lane = tid & 63, wave = tid >> 6;
    const int wm = (wave & 1) * 64, wn = (wave >> 1) * 64;
    const int fr = lane & 15, fq = lane >> 4;
    floatx4 acc[4][4] = {};
    const int srow = tid >> 1, shalf = (tid & 1) * 16;
    const float* aG = &A[(size_t)(bm + srow) * K + shalf];
    const float* wG = &W[(size_t)(bn + srow) * K + shalf];
    unsigned short* aS = &As[srow * LDH + shalf];
    unsigned short* wS = &Ws[srow * LDH + shalf];
    for (int k0 = 0; k0 < K; k0 += 32) {
        floatx4 a0 = *(const floatx4*)(aG + k0);
        floatx4 a1 = *(const floatx4*)(aG + k0 + 4);
        floatx4 a2 = *(const floatx4*)(aG + k0 + 8);
        floatx4 a3 = *(const floatx4*)(aG + k0 + 12);
        floatx4 w0 = *(const floatx4*)(wG + k0);
        floatx4 w1 = *(const floatx4*)(wG + k0 + 4);
        floatx4 w2 = *(const floatx4*)(wG + k0 + 8);
        floatx4 w3 = *(const floatx4*)(wG + k0 + 12);
        __syncthreads();
        *(ushort8*)(aS)     = pack8(a0, a1);
        *(ushort8*)(aS + 8) = pack8(a2, a3);
        *(ushort8*)(wS)     = pack8(w0, w1);
        *(ushort8*)(wS + 8) = pack8(w2, w3);
        __syncthreads();
        short8 af[4], bfr[4];
#pragma unroll
        for (int i = 0; i < 4; i++) {
            af[i]  = *(const short8*)&As[(wm + i * 16 + fr) * LDH + fq * 8];
            bfr[i] = *(const short8*)&Ws[(wn + i * 16 + fr) * LDH + fq * 8];
        }
#pragma unroll
        for (int mi = 0; mi < 4; mi++)
#pragma unroll
            for (int ni = 0; ni < 4; ni++)
                acc[mi][ni] = __builtin_amdgcn_mfma_f32_16x16x32_bf16(af[mi], bfr[ni], acc[mi][ni], 0, 0, 0);
    }
#pragma unroll
    for (int mi = 0; mi < 4; mi++) {
#pragma unroll
        for (int r = 0; r < 4; r++) {
            int row = bm + wm + mi * 16 + fq * 4 + r;
#pragma unroll
            for (int ni = 0; ni < 4; ni++) {
                int col = bn + wn + ni * 16 + fr;
                float v = acc[mi][ni][r] + bias[col];
                if (RES) v += res[(size_t)row * Nn + col];
                if (ACT == 1) v = 0.5f * v * (1.0f + erff(v * 0.70710678118654752f));
                C[(size_t)row * Nn + col] = v;
            }
        }
    }
}

// ---------------- K3b: SAGE MFMA GEMM  pre[N,256] = [agg|g](bf16) @ [wl|wr]^T + bl ----------------
// M = NPAD (tail rows clamped), N = 256, K = 512. Same fragment scheme as K3.
__global__ __launch_bounds__(256) void sage_mfma_kernel(const unsigned short* __restrict__ agg_bf,
                                                        const unsigned short* __restrict__ g_bf,
                                                        const float* __restrict__ wl,
                                                        const float* __restrict__ wr,
                                                        const float* __restrict__ bl,
                                                        float* __restrict__ pre) {
    constexpr int LDH = 40;
    __shared__ unsigned short As[128 * LDH];
    __shared__ unsigned short Ws[128 * LDH];
    const int bm = blockIdx.y * 128, bn = blockIdx.x * 128;
    const int tid = threadIdx.x;
    const int lane = tid & 63, wave = tid >> 6;
    const int wm = (wave & 1) * 64, wn = (wave >> 1) * 64;
    const int fr = lane & 15, fq = lane >> 4;
    floatx4 acc[4][4] = {};
    const int srow = tid >> 1, shalf = (tid & 1) * 16;
    int an = bm + srow; if (an >= NN) an = NN - 1;          // clamp tail rows (stores guarded)
    const int outc = bn + srow;                             // 0..255, always valid
    unsigned short* aS = &As[srow * LDH + shalf];
    unsigned short* wS = &Ws[srow * LDH + shalf];
    for (int k0 = 0; k0 < 512; k0 += 32) {
        int kg = k0 + shalf;                                // segment never straddles 256
        const unsigned short* asrc = (kg < 256) ? &agg_bf[(size_t)an * 256 + kg]
                                                : &g_bf[(size_t)an * 256 + (kg - 256)];
        const float* bsrc = (kg < 256) ? &wl[(size_t)outc * 256 + kg]
                                       : &wr[(size_t)outc * 256 + (kg - 256)];
        ushort8 alo = *(const ushort8*)asrc;
        ushort8 ahi = *(const ushort8*)(asrc + 8);
        floatx4 w0 = *(const floatx4*)(bsrc);
        floatx4 w1 = *(const floatx4*)(bsrc + 4);
        floatx4 w2 = *(const floatx4*)(bsrc + 8);
        floatx4 w3 = *(const floatx4*)(bsrc + 12);
        __syncthreads();
        *(ushort8*)(aS)     = alo;
        *(ushort8*)(aS + 8) = ahi;
        *(ushort8*)(wS)     = pack8(w0, w1);
        *(ushort8*)(wS + 8) = pack8(w2, w3);
        __syncthreads();
        short8 af[4], bfr[4];
#pragma unroll
        for (int i = 0; i < 4; i++) {
            af[i]  = *(const short8*)&As[(wm + i * 16 + fr) * LDH + fq * 8];
            bfr[i] = *(const short8*)&Ws[(wn + i * 16 + fr) * LDH + fq * 8];
        }
#pragma unroll
        for (int mi = 0; mi < 4; mi++)
#pragma unroll
            for (int ni = 0; ni < 4; ni++)
                acc[mi][ni] = __builtin_amdgcn_mfma_f32_16x16x32_bf16(af[mi], bfr[ni], acc[mi][ni], 0, 0, 0);
    }
#pragma unroll
    for (int mi = 0; mi < 4; mi++) {
#pragma unroll
        for (int r = 0; r < 4; r++) {
            int row = bm + wm + mi * 16 + fq * 4 + r;
            if (row < NN) {
#pragma unroll
                for (int ni = 0; ni < 4; ni++) {
                    int col = bn + wn + ni * 16 + fr;
                    pre[(size_t)row * 256 + col] = acc[mi][ni][r] + bl[col];
                }
            }
        }
    }
}

// ---------------- K3c: residual + LN(256) + ReLU -> g_bf (in place) ----------------
__global__ __launch_bounds__(256) void ln_relu_kernel(const float* __restrict__ pre,
                                                      unsigned short* __restrict__ g_bf,
                                                      const float* __restrict__ gnw,
                                                      const float* __restrict__ gnb) {
    int n = blockIdx.x, tid = threadIdx.x;
    float res = ubf(g_bf[(size_t)n * 256 + tid]);
    float v = pre[(size_t)n * 256 + tid] + res;
    __shared__ float p1[4], p2[4];
    float s1 = waveRed(v);
    float s2 = waveRed(v * v);
    if ((tid & 63) == 0) { p1[tid >> 6] = s1; p2[tid >> 6] = s2; }
    __syncthreads();
    float S1 = p1[0] + p1[1] + p1[2] + p1[3];
    float S2 = p2[0] + p2[1] + p2[2] + p2[3];
    float mu = S1 / 256.0f, var = S2 / 256.0f - mu * mu;
    float rs = rsqrtf(fmaxf(var, 0.0f) + 1e-5f);
    float r = (v - mu) * rs * gnw[tid] + gnb[tid];
    g_bf[(size_t)n * 256 + tid] = f2bf(fmaxf(r, 0.0f));
}

// ---------------- K4: fused attention, 8 queries per block ----------------
__global__ __launch_bounds__(256) void attn_kernel(const float* __restrict__ qkv, float* __restrict__ o) {
    int blk = blockIdx.x;            // B*NH*(S/8) = 4096
    int qt = blk & 63;
    int h = (blk >> 6) & 7;
    int b = blk >> 9;
    int q0 = qt * 8;
    int tid = threadIdx.x;
    __shared__ float qv[8][64];
    __shared__ float sc[8][512];
    __shared__ float red[256];
    __shared__ float rowsum[8];
    for (int i = tid; i < 512; i += 256) {
        int q = i >> 6, d = i & 63;
        qv[q][d] = qkv[(size_t)(b * S + q0 + q) * (3 * D) + h * 64 + d];
    }
    __syncthreads();
    for (int k = tid; k < 512; k += 256) {
        const float4* kp4 = (const float4*)&qkv[(size_t)(b * S + k) * (3 * D) + D + h * 64];
        float acc[8] = {};
#pragma unroll 4
        for (int d4 = 0; d4 < 16; d4++) {
            float4 kv = kp4[d4];
#pragma unroll
            for (int q = 0; q < 8; q++) {
                float4 qq = *(const float4*)&qv[q][4 * d4];
                acc[q] += qq.x * kv.x + qq.y * kv.y + qq.z * kv.z + qq.w * kv.w;
            }
        }
#pragma unroll
        for (int q = 0; q < 8; q++) sc[q][k] = acc[q] * 0.125f;
    }
    __syncthreads();
    int q = tid >> 5, l = tid & 31;
    float m = -1e30f;
    for (int k = l; k < 512; k += 32) m = fmaxf(m, sc[q][k]);
    red[tid] = m; __syncthreads();
    for (int off = 16; off; off >>= 1) { if (l < off) red[tid] = fmaxf(red[tid], red[tid + off]); __syncthreads(); }
    float mx = red[q * 32];
    float ssum = 0.0f;
    for (int k = l; k < 512; k += 32) { float p = expf(sc[q][k] - mx); sc[q][k] = p; ssum += p; }
    __syncthreads();
    red[tid] = ssum; __syncthreads();
    for (int off = 16; off; off >>= 1) { if (l < off) red[tid] += red[tid + off]; __syncthreads(); }
    if (l == 0) rowsum[q] = red[q * 32];
    __syncthreads();
    int d = tid & 63, g2 = tid >> 6;
    int qa = g2 * 2, qb = qa + 1;
    float a0 = 0.0f, a1 = 0.0f;
    for (int k = 0; k < 512; k++) {
        float vv = qkv[(size_t)(b * S + k) * (3 * D) + 2 * D + h * 64 + d];
        a0 += sc[qa][k] * vv;
        a1 += sc[qb][k] * vv;
    }
    o[(size_t)(b * S + q0 + qa) * D + h * 64 + d] = a0 / rowsum[qa];
    o[(size_t)(b * S + q0 + qb) * D + h * 64 + d] = a1 / rowsum[qb];
}

// ---------------- K5: masked mean pool over S ----------------
__global__ __launch_bounds__(256) void logpool_kernel(const float* __restrict__ hf, float* __restrict__ lp) {
    int idx = blockIdx.x * 256 + threadIdx.x;
    int b = idx >> 9, d = idx & 511;
    float s = 0.0f;
    for (int t = 0; t < 512; t++) s += hf[(size_t)(b * 512 + t) * 512 + d];
    lp[idx] = s * (1.0f / 512.0f);
}

// ---------------- K6: node encoder -> g_bf ----------------
__global__ __launch_bounds__(256) void node_enc_kernel(const float* __restrict__ x,
                                                       const int* __restrict__ ntype,
                                                       const float* __restrict__ glnw,
                                                       const float* __restrict__ glnb,
                                                       const float* __restrict__ gw,
                                                       const float* __restrict__ gb,
                                                       const float* __restrict__ temb,
                                                       unsigned short* __restrict__ g_bf) {
    int n = blockIdx.x, tid = threadIdx.x;
    int t = ntype[n];
    __shared__ float xa[64];
    __shared__ float stat[2];
    float v = 0.0f;
    if (tid < 64) {
        v = x[(size_t)n * 64 + tid];
        v = fminf(10.0f, fmaxf(-10.0f, v));
        float s1 = waveRed(v);
        float s2 = waveRed(v * v);
        if (tid == 0) { stat[0] = s1; stat[1] = s2; }
    }
    __syncthreads();
    if (tid < 64) {
        float mu = stat[0] / 64.0f;
        float var = stat[1] / 64.0f - mu * mu;
        float rs = rsqrtf(fmaxf(var, 0.0f) + 1e-5f);
        xa[tid] = (v - mu) * rs * glnw[t * 64 + tid] + glnb[t * 64 + tid];
    }
    __syncthreads();
    const float4* w4 = (const float4*)(gw + ((size_t)t * 256 + tid) * 64);
    float acc = 0.0f;
#pragma unroll 4
    for (int f4 = 0; f4 < 16; f4++) {
        float4 u = w4[f4];
        acc += xa[4 * f4 + 0] * u.x + xa[4 * f4 + 1] * u.y
             + xa[4 * f4 + 2] * u.z + xa[4 * f4 + 3] * u.w;
    }
    g_bf[(size_t)n * 256 + tid] = f2bf(acc + gb[t * 256 + tid] + temb[t * 256 + tid]);
}

// ---------------- CSR build ----------------
__global__ __launch_bounds__(256) void hist_kernel(const int* __restrict__ dst, int* __restrict__ deg) {
    int e = blockIdx.x * 256 + threadIdx.x;
    if (e < EE) atomicAdd(&deg[dst[e]], 1);
}

__global__ __launch_bounds__(256) void scan_kernel(const int* __restrict__ deg,
                                                   int* __restrict__ row_start,
                                                   int* __restrict__ cursor) {
    constexpr int CH = (NN + 255) / 256;
    int tid = threadIdx.x;
    __shared__ int part[256];
    int begin = tid * CH;
    int sum = 0;
    for (int i = 0; i < CH; i++) { int idx = begin + i; if (idx < NN) sum += deg[idx]; }
    part[tid] = sum;
    __syncthreads();
    for (int off = 1; off < 256; off <<= 1) {
        int t = (tid >= off) ? part[tid - off] : 0;
        __syncthreads();
        part[tid] += t;
        __syncthreads();
    }
    int run = part[tid] - sum;
    for (int i = 0; i < CH; i++) {
        int idx = begin + i;
        if (idx < NN) {
            row_start[idx] = run; cursor[idx] = run;
            run += deg[idx];
        }
    }
    if (tid == 255) row_start[NN] = run;
}

__global__ __launch_bounds__(256) void fill_kernel(const int* __restrict__ src,
                                                   const int* __restrict__ dst,
                                                   int* __restrict__ cursor,
                                                   int* __restrict__ csr_src) {
    int e = blockIdx.x * 256 + threadIdx.x;
    if (e < EE) {
        int pos = atomicAdd(&cursor[dst[e]], 1);
        csr_src[pos] = src[e];
    }
}

// ---------------- K8: gather-mean aggregation (bf16 in, bf16 out) ----------------
__global__ __launch_bounds__(256) void gather_mean_kernel(const unsigned short* __restrict__ g_bf,
                                                          const int* __restrict__ csr_src,
                                                          const int* __restrict__ row_start,
                                                          unsigned short* __restrict__ agg_bf) {
    int n = blockIdx.x, tid = threadIdx.x;
    int beg = row_start[n], end = row_start[n + 1];
    float acc = 0.0f;
    for (int i = beg; i < end; i++) {
        int s = csr_src[i];
        acc += ubf(g_bf[(size_t)s * 256 + tid]);
    }
    float den = (end > beg) ? (float)(end - beg) : 1.0f;
    agg_bf[(size_t)n * 256 + tid] = f2bf(acc / den);
}

// ---------------- K11: column mean over N nodes ----------------
__global__ __launch_bounds__(256) void gpool_kernel(const unsigned short* __restrict__ g_bf,
                                                    float* __restrict__ psum) {
    int tid = threadIdx.x, blk = blockIdx.x;
    float acc = 0.0f;
    for (int n = blk; n < NN; n += 256) acc += ubf(g_bf[(size_t)n * 256 + tid]);
    atomicAdd(&psum[tid], acc);
}

// ---------------- K12: fusion linear + LN + ReLU -> f32 out ----------------
__global__ __launch_bounds__(256) void fusion_kernel(const float* __restrict__ lp,
                                                     const float* __restrict__ psum,
                                                     const float* __restrict__ fw,
                                                     const float* __restrict__ fb,
                                                     const float* __restrict__ flnw,
                                                     const float* __restrict__ flnb,
                                                     float* __restrict__ out) {
    int b = blockIdx.x, tid = threadIdx.x;
    __shared__ float fin[768], fo[768];
    __shared__ float p1[4], p2[4];
    for (int i = tid; i < 512; i += 256) fin[i] = lp[b * 512 + i];
    if (tid < 256) fin[512 + tid] = psum[tid] * (1.0f / 50000.0f);
    __syncthreads();
    for (int j = tid; j < 768; j += 256) {
        float acc = fb[j];
        const float4* w4 = (const float4*)(fw + (size_t)j * 768);
#pragma unroll 4
        for (int i4 = 0; i4 < 192; i4++) {
            float4 u = w4[i4];
            acc += fin[4 * i4 + 0] * u.x + fin[4 * i4 + 1] * u.y
                 + fin[4 * i4 + 2] * u.z + fin[4 * i4 + 3] * u.w;
        }
        fo[j] = acc;
    }
    __syncthreads();
    float s1 = 0.0f, s2 = 0.0f;
    for (int j = tid; j < 768; j += 256) { float vv = fo[j]; s1 += vv; s2 += vv * vv; }
    s1 = waveRed(s1); s2 = waveRed(s2);
    if ((tid & 63) == 0) { p1[tid >> 6] = s1; p2[tid >> 6] = s2; }
    __syncthreads();
    float S1 = p1[0] + p1[1] + p1[2] + p1[3];
    float S2 = p2[0] + p2[1] + p2[2] + p2[3];
    float mu = S1 / 768.0f, var = S2 / 768.0f - mu * mu;
    float rs = rsqrtf(fmaxf(var, 0.0f) + 1e-5f);
    for (int j = tid; j < 768; j += 256) {
        float r = (fo[j] - mu) * rs * flnw[j] + flnb[j];
        out[b * 768 + j] = fmaxf(r, 0.0f);
    }
}

extern "C" void kernel_launch(void* const* d_in, const int* in_sizes, int n_in,
                              void* d_out, int out_size, void* d_ws, size_t ws_size,
                              hipStream_t stream) {
    (void)in_sizes; (void)n_in; (void)out_size; (void)ws_size;
    const float* tok_emb = (const float*)d_in[0];
    const float* qkv_w   = (const float*)d_in[1];
    const float* qkv_b   = (const float*)d_in[2];
    const float* out_w   = (const float*)d_in[3];
    const float* out_b   = (const float*)d_in[4];
    const float* ln1_w   = (const float*)d_in[5];
    const float* ln1_b   = (const float*)d_in[6];
    const float* ln2_w   = (const float*)d_in[7];
    const float* ln2_b   = (const float*)d_in[8];
    const float* ff1_w   = (const float*)d_in[9];
    const float* ff1_b   = (const float*)d_in[10];
    const float* ff2_w   = (const float*)d_in[11];
    const float* ff2_b   = (const float*)d_in[12];
    const float* fln_w   = (const float*)d_in[13];
    const float* fln_b   = (const float*)d_in[14];
    const float* x       = (const float*)d_in[15];
    const float* gln_w   = (const float*)d_in[16];
    const float* gln_b   = (const float*)d_in[17];
    const float* gw      = (const float*)d_in[18];
    const float* gb      = (const float*)d_in[19];
    const float* temb    = (const float*)d_in[20];
    const float* sage_wl = (const float*)d_in[21];
    const float* sage_bl = (const float*)d_in[22];
    const float* sage_wr = (const float*)d_in[23];
    const float* gnorm_w = (const float*)d_in[24];
    const float* gnorm_b = (const float*)d_in[25];
    const float* fusion_w   = (const float*)d_in[26];
    const float* fusion_b   = (const float*)d_in[27];
    const float* fusion_lnw = (const float*)d_in[28];
    const float* fusion_lnb = (const float*)d_in[29];
    const int* input_ids  = (const int*)d_in[30];
    // d_in[31] = attention_mask: all-true, unused
    const int* edge_index = (const int*)d_in[32];
    const int* node_type  = (const int*)d_in[33];
    const int* e_src = edge_index;
    const int* e_dst = edge_index + EE;

    // workspace layout (float units)
    float* ws  = (float*)d_ws;
    float* h   = ws;                      // [0, 2.1M)
    float* y   = ws + 2097152;            // [2.1M, 4.2M)
    float* qkv = ws + 4194304;            // 6.29M floats
    float* ff  = ws + 4194304;            // 8.39M floats (aliases qkv)
    float* pre = ws;                      // NPAD*256 = 12,812,288 floats; aliases h/y/qkv (dead after logpool)
    unsigned short* g_bf   = (unsigned short*)(ws + 12812288);   // 12,812,288 ushorts = 6,406,144 floats
    unsigned short* agg_bf = (unsigned short*)(ws + 19218432);   // same size
    float* lp   = ws + 25624576;          // 4096
    float* psum = ws + 25628672;          // 256
    int* ibase     = (int*)(ws + 25628928);
    int* deg_i     = ibase;               // 50,000
    int* row_start = ibase + 50000;       // 50,001
    int* cursor    = ibase + 100001;      // 50,000
    int* csr_src   = ibase + 150001;      // 800,000
    // total: 26,578,929 floats = 106.3 MB

    // ---- transformer ----
    embed_kernel<<<T, 256, 0, stream>>>(tok_emb, input_ids, h);
    for (int l = 0; l < L; l++) {
        ln512_kernel<<<T, 256, 0, stream>>>(h, ln1_w + l * D, ln1_b + l * D, y);
        mfma_gemm_kernel<0, false><<<dim3(3 * D / 128, T / 128), 256, 0, stream>>>(
            y, qkv_w + (size_t)l * 3 * D * D, qkv_b + (size_t)l * 3 * D, nullptr, qkv, T, 3 * D, D);
        attn_kernel<<<B * NH * (S / 8), 256, 0, stream>>>(qkv, y);   // o -> y
        mfma_gemm_kernel<0, true><<<dim3(D / 128, T / 128), 256, 0, stream>>>(
            y, out_w + (size_t)l * D * D, out_b + (size_t)l * D, h, h, T, D, D);
        ln512_kernel<<<T, 256, 0, stream>>>(h, ln2_w + l * D, ln2_b + l * D, y);
        mfma_gemm_kernel<1, false><<<dim3(FF / 128, T / 128), 256, 0, stream>>>(
            y, ff1_w + (size_t)l * FF * D, ff1_b + (size_t)l * FF, nullptr, ff, T, FF, D);
        mfma_gemm_kernel<0, true><<<dim3(D / 128, T / 128), 256, 0, stream>>>(
            ff, ff2_w + (size_t)l * D * FF, ff2_b + (size_t)l * D, h, h, T, D, FF);
    }
    ln512_kernel<<<T, 256, 0, stream>>>(h, fln_w, fln_b, y);
    logpool_kernel<<<(B * D) / 256, 256, 0, stream>>>(y, lp);

    // ---- graph: node encode + CSR build + 2 SAGE layers (MFMA) ----
    node_enc_kernel<<<NN, 256, 0, stream>>>(x, node_type, gln_w, gln_b, gw, gb, temb, g_bf);
    hipMemsetAsync(deg_i, 0, NN * sizeof(int), stream);
    hist_kernel<<<(EE + 255) / 256, 256, 0, stream>>>(e_dst, deg_i);
    scan_kernel<<<1, 256, 0, stream>>>(deg_i, row_start, cursor);
    fill_kernel<<<(EE + 255) / 256, 256, 0, stream>>>(e_src, e_dst, cursor, csr_src);
    for (int l = 0; l < 2; l++) {
        gather_mean_kernel<<<NN, 256, 0, stream>>>(g_bf, csr_src, row_start, agg_bf);
        sage_mfma_kernel<<<dim3(2, NPAD / 128), 256, 0, stream>>>(agg_bf, g_bf,
            sage_wl + (size_t)l * HG * HG, sage_wr + (size_t)l * HG * HG, sage_bl + (size_t)l * HG, pre);
        ln_relu_kernel<<<NN, 256, 0, stream>>>(pre, g_bf,
            gnorm_w + (size_t)l * HG, gnorm_b + (size_t)l * HG);
    }
    hipMemsetAsync(psum, 0, HG * sizeof(float), stream);
    gpool_kernel<<<256, 256, 0, stream>>>(g_bf, psum);
    fusion_kernel<<<B, 256, 0, stream>>>(lp, psum, fusion_w, fusion_b, fusion_lnw, fusion_lnb,
                                         (float*)d_out);
}

// Round 5
// 2340.002 us; speedup vs baseline: 5.1337x; 1.3708x over previous
//
#include <hip/hip_runtime.h>
#include <hip/hip_bf16.h>
#include <math.h>

#define DEVINL __device__ __forceinline__

constexpr int L = 4, D = 512, FF = 2048, NH = 8, DH = 64, B = 8, S = 512;
constexpr int NN = 50000, EE = 800000, HG = 256, FUS = 768;
constexpr int T = B * S;     // 4096 tokens
constexpr int NPAD = 50048;  // 391 * 128

typedef __attribute__((ext_vector_type(8))) short short8;
typedef __attribute__((ext_vector_type(8))) unsigned short ushort8;
typedef __attribute__((ext_vector_type(4))) float floatx4;

DEVINL float waveRed(float v) { for (int o = 32; o; o >>= 1) v += __shfl_down(v, o); return v; }

DEVINL float ubf(unsigned int u) { union { unsigned int i; float f; } c; c.i = u << 16; return c.f; }
DEVINL unsigned short f2bf(float f) {
    union { float f; unsigned int u; } c; c.f = f;
    unsigned int r = c.u + 0x7fffu + ((c.u >> 16) & 1u);   // RNE
    return (unsigned short)(r >> 16);
}
DEVINL ushort8 pack8(floatx4 x, floatx4 y) {
    ushort8 r;
    r[0] = f2bf(x[0]); r[1] = f2bf(x[1]); r[2] = f2bf(x[2]); r[3] = f2bf(x[3]);
    r[4] = f2bf(y[0]); r[5] = f2bf(y[1]); r[6] = f2bf(y[2]); r[7] = f2bf(y[3]);
    return r;
}

// ---------------- K1: embedding + sinusoidal PE -> h (f32) ----------------
__global__ __launch_bounds__(256) void embed_kernel(const float* __restrict__ tok,
                                                    const int* __restrict__ ids, float* __restrict__ h) {
    int t = blockIdx.x;
    int s = t & (S - 1);
    int id = ids[t];
    const float scale = 22.62741699796952f;               // sqrt(512)
    const float kln = 9.210340371976184f / 512.0f;        // ln(10000)/D
    for (int d = threadIdx.x; d < D; d += 256) {
        float e = tok[(size_t)id * D + d] * scale;
        float ang = (float)s * expf(-(float)(2 * (d >> 1)) * kln);
        float pe = (d & 1) ? cosf(ang) : sinf(ang);
        h[(size_t)t * D + d] = e + pe;
    }
}

// ---------------- K2: LayerNorm over D=512 ----------------
__global__ __launch_bounds__(256) void ln512_kernel(const float* __restrict__ in,
                                                    const float* __restrict__ w,
                                                    const float* __restrict__ bb,
                                                    float* __restrict__ out) {
    int t = blockIdx.x, tid = threadIdx.x;
    const float* row = in + (size_t)t * 512;
    float v0 = row[tid], v1 = row[tid + 256];
    float s1 = waveRed(v0 + v1);
    float s2 = waveRed(v0 * v0 + v1 * v1);
    __shared__ float p1[4], p2[4];
    if ((tid & 63) == 0) { p1[tid >> 6] = s1; p2[tid >> 6] = s2; }
    __syncthreads();
    float S1 = p1[0] + p1[1] + p1[2] + p1[3];
    float S2 = p2[0] + p2[1] + p2[2] + p2[3];
    float mu = S1 / 512.0f, var = S2 / 512.0f - mu * mu;
    float rs = rsqrtf(fmaxf(var, 0.0f) + 1e-5f);
    out[(size_t)t * 512 + tid]       = (v0 - mu) * rs * w[tid]       + bb[tid];
    out[(size_t)t * 512 + tid + 256] = (v1 - mu) * rs * w[tid + 256] + bb[tid + 256];
}

// ---------------- K3: bf16 MFMA GEMM  C[M,N] = act(A[M,K] @ W[N,K]^T + bias (+res)) ----------------
template <int ACT, bool RES>
__global__ __launch_bounds__(256) void mfma_gemm_kernel(const float* __restrict__ A,
                                                        const float* __restrict__ W,
                                                        const float* __restrict__ bias,
                                                        const float* __restrict__ res,
                                                        float* __restrict__ C, int M, int Nn, int K) {
    constexpr int LDH = 40;
    __shared__ unsigned short As[128 * LDH];
    __shared__ unsigned short Ws[128 * LDH];
    const int bm = blockIdx.y * 128, bn = blockIdx.x * 128;
    const int tid = threadIdx.x;
    const int lane = tid & 63, wave = tid >> 6;
    const int wm = (wave & 1) * 64, wn = (wave >> 1) * 64;
    const int fr = lane & 15, fq = lane >> 4;
    floatx4 acc[4][4] = {};
    const int srow = tid >> 1, shalf = (tid & 1) * 16;
    const float* aG = &A[(size_t)(bm + srow) * K + shalf];
    const float* wG = &W[(size_t)(bn + srow) * K + shalf];
    unsigned short* aS = &As[srow * LDH + shalf];
    unsigned short* wS = &Ws[srow * LDH + shalf];
    for (int k0 = 0; k0 < K; k0 += 32) {
        floatx4 a0 = *(const floatx4*)(aG + k0);
        floatx4 a1 = *(const floatx4*)(aG + k0 + 4);
        floatx4 a2 = *(const floatx4*)(aG + k0 + 8);
        floatx4 a3 = *(const floatx4*)(aG + k0 + 12);
        floatx4 w0 = *(const floatx4*)(wG + k0);
        floatx4 w1 = *(const floatx4*)(wG + k0 + 4);
        floatx4 w2 = *(const floatx4*)(wG + k0 + 8);
        floatx4 w3 = *(const floatx4*)(wG + k0 + 12);
        __syncthreads();
        *(ushort8*)(aS)     = pack8(a0, a1);
        *(ushort8*)(aS + 8) = pack8(a2, a3);
        *(ushort8*)(wS)     = pack8(w0, w1);
        *(ushort8*)(wS + 8) = pack8(w2, w3);
        __syncthreads();
        short8 af[4], bfr[4];
#pragma unroll
        for (int i = 0; i < 4; i++) {
            af[i]  = *(const short8*)&As[(wm + i * 16 + fr) * LDH + fq * 8];
            bfr[i] = *(const short8*)&Ws[(wn + i * 16 + fr) * LDH + fq * 8];
        }
#pragma unroll
        for (int mi = 0; mi < 4; mi++)
#pragma unroll
            for (int ni = 0; ni < 4; ni++)
                acc[mi][ni] = __builtin_amdgcn_mfma_f32_16x16x32_bf16(af[mi], bfr[ni], acc[mi][ni], 0, 0, 0);
    }
#pragma unroll
    for (int mi = 0; mi < 4; mi++) {
#pragma unroll
        for (int r = 0; r < 4; r++) {
            int row = bm + wm + mi * 16 + fq * 4 + r;
#pragma unroll
            for (int ni = 0; ni < 4; ni++) {
                int col = bn + wn + ni * 16 + fr;
                float v = acc[mi][ni][r] + bias[col];
                if (RES) v += res[(size_t)row * Nn + col];
                if (ACT == 1) v = 0.5f * v * (1.0f + erff(v * 0.70710678118654752f));
                C[(size_t)row * Nn + col] = v;
            }
        }
    }
}

// ---------------- K3b: SAGE MFMA GEMM  pre[N,256] = [agg|g](bf16) @ [wl|wr]^T + bl ----------------
__global__ __launch_bounds__(256) void sage_mfma_kernel(const unsigned short* __restrict__ agg_bf,
                                                        const unsigned short* __restrict__ g_bf,
                                                        const float* __restrict__ wl,
                                                        const float* __restrict__ wr,
                                                        const float* __restrict__ bl,
                                                        float* __restrict__ pre) {
    constexpr int LDH = 40;
    __shared__ unsigned short As[128 * LDH];
    __shared__ unsigned short Ws[128 * LDH];
    const int bm = blockIdx.y * 128, bn = blockIdx.x * 128;
    const int tid = threadIdx.x;
    const int lane = tid & 63, wave = tid >> 6;
    const int wm = (wave & 1) * 64, wn = (wave >> 1) * 64;
    const int fr = lane & 15, fq = lane >> 4;
    floatx4 acc[4][4] = {};
    const int srow = tid >> 1, shalf = (tid & 1) * 16;
    int an = bm + srow; if (an >= NN) an = NN - 1;
    const int outc = bn + srow;
    unsigned short* aS = &As[srow * LDH + shalf];
    unsigned short* wS = &Ws[srow * LDH + shalf];
    for (int k0 = 0; k0 < 512; k0 += 32) {
        int kg = k0 + shalf;
        const unsigned short* asrc = (kg < 256) ? &agg_bf[(size_t)an * 256 + kg]
                                                : &g_bf[(size_t)an * 256 + (kg - 256)];
        const float* bsrc = (kg < 256) ? &wl[(size_t)outc * 256 + kg]
                                       : &wr[(size_t)outc * 256 + (kg - 256)];
        ushort8 alo = *(const ushort8*)asrc;
        ushort8 ahi = *(const ushort8*)(asrc + 8);
        floatx4 w0 = *(const floatx4*)(bsrc);
        floatx4 w1 = *(const floatx4*)(bsrc + 4);
        floatx4 w2 = *(const floatx4*)(bsrc + 8);
        floatx4 w3 = *(const floatx4*)(bsrc + 12);
        __syncthreads();
        *(ushort8*)(aS)     = alo;
        *(ushort8*)(aS + 8) = ahi;
        *(ushort8*)(wS)     = pack8(w0, w1);
        *(ushort8*)(wS + 8) = pack8(w2, w3);
        __syncthreads();
        short8 af[4], bfr[4];
#pragma unroll
        for (int i = 0; i < 4; i++) {
            af[i]  = *(const short8*)&As[(wm + i * 16 + fr) * LDH + fq * 8];
            bfr[i] = *(const short8*)&Ws[(wn + i * 16 + fr) * LDH + fq * 8];
        }
#pragma unroll
        for (int mi = 0; mi < 4; mi++)
#pragma unroll
            for (int ni = 0; ni < 4; ni++)
                acc[mi][ni] = __builtin_amdgcn_mfma_f32_16x16x32_bf16(af[mi], bfr[ni], acc[mi][ni], 0, 0, 0);
    }
#pragma unroll
    for (int mi = 0; mi < 4; mi++) {
#pragma unroll
        for (int r = 0; r < 4; r++) {
            int row = bm + wm + mi * 16 + fq * 4 + r;
            if (row < NN) {
#pragma unroll
                for (int ni = 0; ni < 4; ni++) {
                    int col = bn + wn + ni * 16 + fr;
                    pre[(size_t)row * 256 + col] = acc[mi][ni][r] + bl[col];
                }
            }
        }
    }
}

// ---------------- K3c: residual + LN(256) + ReLU -> g_bf (in place) ----------------
__global__ __launch_bounds__(256) void ln_relu_kernel(const float* __restrict__ pre,
                                                      unsigned short* __restrict__ g_bf,
                                                      const float* __restrict__ gnw,
                                                      const float* __restrict__ gnb) {
    int n = blockIdx.x, tid = threadIdx.x;
    float res = ubf(g_bf[(size_t)n * 256 + tid]);
    float v = pre[(size_t)n * 256 + tid] + res;
    __shared__ float p1[4], p2[4];
    float s1 = waveRed(v);
    float s2 = waveRed(v * v);
    if ((tid & 63) == 0) { p1[tid >> 6] = s1; p2[tid >> 6] = s2; }
    __syncthreads();
    float S1 = p1[0] + p1[1] + p1[2] + p1[3];
    float S2 = p2[0] + p2[1] + p2[2] + p2[3];
    float mu = S1 / 256.0f, var = S2 / 256.0f - mu * mu;
    float rs = rsqrtf(fmaxf(var, 0.0f) + 1e-5f);
    float r = (v - mu) * rs * gnw[tid] + gnb[tid];
    g_bf[(size_t)n * 256 + tid] = f2bf(fmaxf(r, 0.0f));
}

// ---------------- K4: fused attention, 8 queries per block ----------------
__global__ __launch_bounds__(256) void attn_kernel(const float* __restrict__ qkv, float* __restrict__ o) {
    int blk = blockIdx.x;            // B*NH*(S/8) = 4096
    int qt = blk & 63;
    int h = (blk >> 6) & 7;
    int b = blk >> 9;
    int q0 = qt * 8;
    int tid = threadIdx.x;
    __shared__ float qv[8][64];
    __shared__ float sc[8][512];
    __shared__ float red[256];
    __shared__ float rowsum[8];
    for (int i = tid; i < 512; i += 256) {
        int q = i >> 6, d = i & 63;
        qv[q][d] = qkv[(size_t)(b * S + q0 + q) * (3 * D) + h * 64 + d];
    }
    __syncthreads();
    for (int k = tid; k < 512; k += 256) {
        const float4* kp4 = (const float4*)&qkv[(size_t)(b * S + k) * (3 * D) + D + h * 64];
        float acc[8] = {};
#pragma unroll 4
        for (int d4 = 0; d4 < 16; d4++) {
            float4 kv = kp4[d4];
#pragma unroll
            for (int q = 0; q < 8; q++) {
                float4 qq = *(const float4*)&qv[q][4 * d4];
                acc[q] += qq.x * kv.x + qq.y * kv.y + qq.z * kv.z + qq.w * kv.w;
            }
        }
#pragma unroll
        for (int q = 0; q < 8; q++) sc[q][k] = acc[q] * 0.125f;
    }
    __syncthreads();
    int q = tid >> 5, l = tid & 31;
    float m = -1e30f;
    for (int k = l; k < 512; k += 32) m = fmaxf(m, sc[q][k]);
    red[tid] = m; __syncthreads();
    for (int off = 16; off; off >>= 1) { if (l < off) red[tid] = fmaxf(red[tid], red[tid + off]); __syncthreads(); }
    float mx = red[q * 32];
    float ssum = 0.0f;
    for (int k = l; k < 512; k += 32) { float p = expf(sc[q][k] - mx); sc[q][k] = p; ssum += p; }
    __syncthreads();
    red[tid] = ssum; __syncthreads();
    for (int off = 16; off; off >>= 1) { if (l < off) red[tid] += red[tid + off]; __syncthreads(); }
    if (l == 0) rowsum[q] = red[q * 32];
    __syncthreads();
    int d = tid & 63, g2 = tid >> 6;
    int qa = g2 * 2, qb = qa + 1;
    // P @ V with 4-deep MLP: 4 independent V loads + float4 LDS prob reads
    const float* vp0 = &qkv[(size_t)(b * S) * 1536 + 1024 + h * 64 + d];
    float s0 = 0, s1 = 0, s2 = 0, s3 = 0;
    float t0 = 0, t1 = 0, t2 = 0, t3 = 0;
    for (int k = 0; k < 512; k += 4) {
        const float* vp = vp0 + (size_t)k * 1536;
        float v0 = vp[0], v1 = vp[1536], v2 = vp[3072], v3 = vp[4608];
        float4 pa = *(const float4*)&sc[qa][k];
        float4 pb = *(const float4*)&sc[qb][k];
        s0 += pa.x * v0; s1 += pa.y * v1; s2 += pa.z * v2; s3 += pa.w * v3;
        t0 += pb.x * v0; t1 += pb.y * v1; t2 += pb.z * v2; t3 += pb.w * v3;
    }
    float a0 = (s0 + s1) + (s2 + s3);
    float a1 = (t0 + t1) + (t2 + t3);
    o[(size_t)(b * S + q0 + qa) * D + h * 64 + d] = a0 / rowsum[qa];
    o[(size_t)(b * S + q0 + qb) * D + h * 64 + d] = a1 / rowsum[qb];
}

// ---------------- K5: masked mean pool over S ----------------
__global__ __launch_bounds__(256) void logpool_kernel(const float* __restrict__ hf, float* __restrict__ lp) {
    int idx = blockIdx.x * 256 + threadIdx.x;
    int b = idx >> 9, d = idx & 511;
    float s = 0.0f;
    for (int t = 0; t < 512; t++) s += hf[(size_t)(b * 512 + t) * 512 + d];
    lp[idx] = s * (1.0f / 512.0f);
}

// ---------------- K6a: node clip + shared LN + per-type affine -> xab bf16 [n][64] ----------------
__global__ __launch_bounds__(256) void node_ln_kernel(const float* __restrict__ x,
                                                      const int* __restrict__ ntype,
                                                      const float* __restrict__ glnw,
                                                      const float* __restrict__ glnb,
                                                      unsigned short* __restrict__ xab) {
    int tid = threadIdx.x;
    int n = blockIdx.x * 4 + (tid >> 6);
    int lane = tid & 63;
    if (n >= NN) return;
    float v = x[(size_t)n * 64 + lane];
    v = fminf(10.0f, fmaxf(-10.0f, v));
    float s1 = waveRed(v);        s1 = __shfl(s1, 0);
    float s2 = waveRed(v * v);    s2 = __shfl(s2, 0);
    float mu = s1 / 64.0f, var = s2 / 64.0f - mu * mu;
    float rs = rsqrtf(fmaxf(var, 0.0f) + 1e-5f);
    int t = ntype[n];
    float r = (v - mu) * rs * glnw[t * 64 + lane] + glnb[t * 64 + lane];
    xab[(size_t)n * 64 + lane] = f2bf(r);
}

// ---------------- K6b: bucket nodes by type (LDS-aggregated) ----------------
__global__ __launch_bounds__(256) void bucket_kernel(const int* __restrict__ ntype,
                                                     int* __restrict__ tcur,
                                                     int* __restrict__ perm) {
    __shared__ int lcnt[3], lbase[3];
    int tid = threadIdx.x;
    int n = blockIdx.x * 256 + tid;
    if (tid < 3) lcnt[tid] = 0;
    __syncthreads();
    int t = 0, lpos = 0;
    bool act = (n < NN);
    if (act) { t = ntype[n]; lpos = atomicAdd(&lcnt[t], 1); }
    __syncthreads();
    if (tid < 3) lbase[tid] = atomicAdd(&tcur[tid], lcnt[tid]);
    __syncthreads();
    if (act) perm[t * NPAD + lbase[t] + lpos] = n;
}

// ---------------- K6c: per-type MFMA GEMM  g[perm[r]][c] = xab[perm[r]] @ gw[t]^T + gb + temb ----------------
// grid (2, NPAD/128, 3); K = 64.
__global__ __launch_bounds__(256) void type_gemm_kernel(const unsigned short* __restrict__ xab,
                                                        const int* __restrict__ perm,
                                                        const int* __restrict__ cnts,
                                                        const float* __restrict__ gw,
                                                        const float* __restrict__ gb,
                                                        const float* __restrict__ temb,
                                                        unsigned short* __restrict__ g_bf) {
    constexpr int LDH = 40;
    __shared__ unsigned short As[128 * LDH];
    __shared__ unsigned short Ws[128 * LDH];
    const int t = blockIdx.z;
    const int cnt = cnts[t];
    const int bm = blockIdx.y * 128, bn = blockIdx.x * 128;
    if (bm >= cnt) return;
    const int tid = threadIdx.x;
    const int lane = tid & 63, wave = tid >> 6;
    const int wm = (wave & 1) * 64, wn = (wave >> 1) * 64;
    const int fr = lane & 15, fq = lane >> 4;
    floatx4 acc[4][4] = {};
    const int srow = tid >> 1, shalf = (tid & 1) * 16;
    int gr = bm + srow; if (gr >= cnt) gr = cnt - 1;
    const int node = perm[t * NPAD + gr];
    const int outc = bn + srow;   // 0..255
    unsigned short* aS = &As[srow * LDH + shalf];
    unsigned short* wS = &Ws[srow * LDH + shalf];
#pragma unroll
    for (int k0 = 0; k0 < 64; k0 += 32) {
        const unsigned short* asrc = &xab[(size_t)node * 64 + k0 + shalf];
        const float* bsrc = &gw[((size_t)t * 256 + outc) * 64 + k0 + shalf];
        ushort8 alo = *(const ushort8*)asrc;
        ushort8 ahi = *(const ushort8*)(asrc + 8);
        floatx4 w0 = *(const floatx4*)(bsrc);
        floatx4 w1 = *(const floatx4*)(bsrc + 4);
        floatx4 w2 = *(const floatx4*)(bsrc + 8);
        floatx4 w3 = *(const floatx4*)(bsrc + 12);
        __syncthreads();
        *(ushort8*)(aS)     = alo;
        *(ushort8*)(aS + 8) = ahi;
        *(ushort8*)(wS)     = pack8(w0, w1);
        *(ushort8*)(wS + 8) = pack8(w2, w3);
        __syncthreads();
        short8 af[4], bfr[4];
#pragma unroll
        for (int i = 0; i < 4; i++) {
            af[i]  = *(const short8*)&As[(wm + i * 16 + fr) * LDH + fq * 8];
            bfr[i] = *(const short8*)&Ws[(wn + i * 16 + fr) * LDH + fq * 8];
        }
#pragma unroll
        for (int mi = 0; mi < 4; mi++)
#pragma unroll
            for (int ni = 0; ni < 4; ni++)
                acc[mi][ni] = __builtin_amdgcn_mfma_f32_16x16x32_bf16(af[mi], bfr[ni], acc[mi][ni], 0, 0, 0);
    }
#pragma unroll
    for (int mi = 0; mi < 4; mi++) {
#pragma unroll
        for (int r = 0; r < 4; r++) {
            int row = bm + wm + mi * 16 + fq * 4 + r;
            if (row < cnt) {
                int nd = perm[t * NPAD + row];
#pragma unroll
                for (int ni = 0; ni < 4; ni++) {
                    int col = bn + wn + ni * 16 + fr;
                    g_bf[(size_t)nd * 256 + col] =
                        f2bf(acc[mi][ni][r] + gb[t * 256 + col] + temb[t * 256 + col]);
                }
            }
        }
    }
}

// ---------------- CSR build ----------------
__global__ __launch_bounds__(256) void hist_kernel(const int* __restrict__ dst, int* __restrict__ deg) {
    int e = blockIdx.x * 256 + threadIdx.x;
    if (e < EE) atomicAdd(&deg[dst[e]], 1);
}

__global__ __launch_bounds__(256) void scan_kernel(const int* __restrict__ deg,
                                                   int* __restrict__ row_start,
                                                   int* __restrict__ cursor) {
    constexpr int CH = (NN + 255) / 256;
    int tid = threadIdx.x;
    __shared__ int part[256];
    int begin = tid * CH;
    int sum = 0;
    for (int i = 0; i < CH; i++) { int idx = begin + i; if (idx < NN) sum += deg[idx]; }
    part[tid] = sum;
    __syncthreads();
    for (int off = 1; off < 256; off <<= 1) {
        int t = (tid >= off) ? part[tid - off] : 0;
        __syncthreads();
        part[tid] += t;
        __syncthreads();
    }
    int run = part[tid] - sum;
    for (int i = 0; i < CH; i++) {
        int idx = begin + i;
        if (idx < NN) {
            row_start[idx] = run; cursor[idx] = run;
            run += deg[idx];
        }
    }
    if (tid == 255) row_start[NN] = run;
}

__global__ __launch_bounds__(256) void fill_kernel(const int* __restrict__ src,
                                                   const int* __restrict__ dst,
                                                   int* __restrict__ cursor,
                                                   int* __restrict__ csr_src) {
    int e = blockIdx.x * 256 + threadIdx.x;
    if (e < EE) {
        int pos = atomicAdd(&cursor[dst[e]], 1);
        csr_src[pos] = src[e];
    }
}

// ---------------- K8: gather-mean (2 nodes/block, bf16-pair/thread, 4-deep MLP) ----------------
__global__ __launch_bounds__(256) void gather_mean_kernel(const unsigned int* __restrict__ g32,
                                                          const int* __restrict__ csr_src,
                                                          const int* __restrict__ row_start,
                                                          unsigned int* __restrict__ agg32) {
    int tid = threadIdx.x;
    int n = blockIdx.x * 2 + (tid >> 7);
    int c = tid & 127;                 // channel pair
    int beg = row_start[n], end = row_start[n + 1];
    float a0 = 0, a1 = 0, a2 = 0, a3 = 0;
    float b0 = 0, b1 = 0, b2 = 0, b3 = 0;
    int i = beg;
    for (; i + 4 <= end; i += 4) {
        int s0 = csr_src[i], s1 = csr_src[i + 1], s2 = csr_src[i + 2], s3 = csr_src[i + 3];
        unsigned int u0 = g32[(size_t)s0 * 128 + c];
        unsigned int u1 = g32[(size_t)s1 * 128 + c];
        unsigned int u2 = g32[(size_t)s2 * 128 + c];
        unsigned int u3 = g32[(size_t)s3 * 128 + c];
        a0 += ubf(u0 & 0xffff); b0 += ubf(u0 >> 16);
        a1 += ubf(u1 & 0xffff); b1 += ubf(u1 >> 16);
        a2 += ubf(u2 & 0xffff); b2 += ubf(u2 >> 16);
        a3 += ubf(u3 & 0xffff); b3 += ubf(u3 >> 16);
    }
    for (; i < end; i++) {
        int s = csr_src[i];
        unsigned int u = g32[(size_t)s * 128 + c];
        a0 += ubf(u & 0xffff); b0 += ubf(u >> 16);
    }
    float den = (end > beg) ? (float)(end - beg) : 1.0f;
    float m0 = ((a0 + a1) + (a2 + a3)) / den;
    float m1 = ((b0 + b1) + (b2 + b3)) / den;
    agg32[(size_t)n * 128 + c] = (unsigned int)f2bf(m0) | ((unsigned int)f2bf(m1) << 16);
}

// ---------------- K11: column mean over N nodes ----------------
__global__ __launch_bounds__(256) void gpool_kernel(const unsigned short* __restrict__ g_bf,
                                                    float* __restrict__ psum) {
    int tid = threadIdx.x, blk = blockIdx.x;
    float acc = 0.0f;
    for (int n = blk; n < NN; n += 256) acc += ubf(g_bf[(size_t)n * 256 + tid]);
    atomicAdd(&psum[tid], acc);
}

// ---------------- K12: fusion linear + LN + ReLU -> f32 out ----------------
__global__ __launch_bounds__(256) void fusion_kernel(const float* __restrict__ lp,
                                                     const float* __restrict__ psum,
                                                     const float* __restrict__ fw,
                                                     const float* __restrict__ fb,
                                                     const float* __restrict__ flnw,
                                                     const float* __restrict__ flnb,
                                                     float* __restrict__ out) {
    int b = blockIdx.x, tid = threadIdx.x;
    __shared__ float fin[768], fo[768];
    __shared__ float p1[4], p2[4];
    for (int i = tid; i < 512; i += 256) fin[i] = lp[b * 512 + i];
    if (tid < 256) fin[512 + tid] = psum[tid] * (1.0f / 50000.0f);
    __syncthreads();
    for (int j = tid; j < 768; j += 256) {
        float acc = fb[j];
        const float4* w4 = (const float4*)(fw + (size_t)j * 768);
#pragma unroll 4
        for (int i4 = 0; i4 < 192; i4++) {
            float4 u = w4[i4];
            acc += fin[4 * i4 + 0] * u.x + fin[4 * i4 + 1] * u.y
                 + fin[4 * i4 + 2] * u.z + fin[4 * i4 + 3] * u.w;
        }
        fo[j] = acc;
    }
    __syncthreads();
    float s1 = 0.0f, s2 = 0.0f;
    for (int j = tid; j < 768; j += 256) { float vv = fo[j]; s1 += vv; s2 += vv * vv; }
    s1 = waveRed(s1); s2 = waveRed(s2);
    if ((tid & 63) == 0) { p1[tid >> 6] = s1; p2[tid >> 6] = s2; }
    __syncthreads();
    float S1 = p1[0] + p1[1] + p1[2] + p1[3];
    float S2 = p2[0] + p2[1] + p2[2] + p2[3];
    float mu = S1 / 768.0f, var = S2 / 768.0f - mu * mu;
    float rs = rsqrtf(fmaxf(var, 0.0f) + 1e-5f);
    for (int j = tid; j < 768; j += 256) {
        float r = (fo[j] - mu) * rs * flnw[j] + flnb[j];
        out[b * 768 + j] = fmaxf(r, 0.0f);
    }
}

extern "C" void kernel_launch(void* const* d_in, const int* in_sizes, int n_in,
                              void* d_out, int out_size, void* d_ws, size_t ws_size,
                              hipStream_t stream) {
    (void)in_sizes; (void)n_in; (void)out_size; (void)ws_size;
    const float* tok_emb = (const float*)d_in[0];
    const float* qkv_w   = (const float*)d_in[1];
    const float* qkv_b   = (const float*)d_in[2];
    const float* out_w   = (const float*)d_in[3];
    const float* out_b   = (const float*)d_in[4];
    const float* ln1_w   = (const float*)d_in[5];
    const float* ln1_b   = (const float*)d_in[6];
    const float* ln2_w   = (const float*)d_in[7];
    const float* ln2_b   = (const float*)d_in[8];
    const float* ff1_w   = (const float*)d_in[9];
    const float* ff1_b   = (const float*)d_in[10];
    const float* ff2_w   = (const float*)d_in[11];
    const float* ff2_b   = (const float*)d_in[12];
    const float* fln_w   = (const float*)d_in[13];
    const float* fln_b   = (const float*)d_in[14];
    const float* x       = (const float*)d_in[15];
    const float* gln_w   = (const float*)d_in[16];
    const float* gln_b   = (const float*)d_in[17];
    const float* gw      = (const float*)d_in[18];
    const float* gb      = (const float*)d_in[19];
    const float* temb    = (const float*)d_in[20];
    const float* sage_wl = (const float*)d_in[21];
    const float* sage_bl = (const float*)d_in[22];
    const float* sage_wr = (const float*)d_in[23];
    const float* gnorm_w = (const float*)d_in[24];
    const float* gnorm_b = (const float*)d_in[25];
    const float* fusion_w   = (const float*)d_in[26];
    const float* fusion_b   = (const float*)d_in[27];
    const float* fusion_lnw = (const float*)d_in[28];
    const float* fusion_lnb = (const float*)d_in[29];
    const int* input_ids  = (const int*)d_in[30];
    // d_in[31] = attention_mask: all-true, unused
    const int* edge_index = (const int*)d_in[32];
    const int* node_type  = (const int*)d_in[33];
    const int* e_src = edge_index;
    const int* e_dst = edge_index + EE;

    // workspace layout (float units)
    float* ws  = (float*)d_ws;
    // region A [0, 12,812,288): transformer h/y/qkv/ff, then (graph phase) xab+perm, then pre
    float* h   = ws;                      // 2,097,152
    float* y   = ws + 2097152;            // 2,097,152
    float* qkv = ws + 4194304;            // 6.29M floats
    float* ff  = ws + 4194304;            // 8.39M floats (aliases qkv)
    unsigned short* xab = (unsigned short*)ws;            // 50048*64 ushorts (dead before pre)
    int* perm  = (int*)(ws + 1601536);    // 3*NPAD = 150,144 ints
    int* tcur  = (int*)(ws + 1751680);    // 3 ints (+pad)
    float* pre = ws;                      // NPAD*256 floats (sage phase)
    unsigned short* g_bf   = (unsigned short*)(ws + 12812288);   // 50048*256 ushorts
    unsigned short* agg_bf = (unsigned short*)(ws + 19218432);
    float* lp   = ws + 25624576;          // 4096
    float* psum = ws + 25628672;          // 256
    int* ibase     = (int*)(ws + 25628928);
    int* deg_i     = ibase;               // 50,000
    int* row_start = ibase + 50000;       // 50,001
    int* cursor    = ibase + 100001;      // 50,000
    int* csr_src   = ibase + 150001;      // 800,000
    // total: 26,578,929 floats = 106.3 MB

    // ---- transformer ----
    embed_kernel<<<T, 256, 0, stream>>>(tok_emb, input_ids, h);
    for (int l = 0; l < L; l++) {
        ln512_kernel<<<T, 256, 0, stream>>>(h, ln1_w + l * D, ln1_b + l * D, y);
        mfma_gemm_kernel<0, false><<<dim3(3 * D / 128, T / 128), 256, 0, stream>>>(
            y, qkv_w + (size_t)l * 3 * D * D, qkv_b + (size_t)l * 3 * D, nullptr, qkv, T, 3 * D, D);
        attn_kernel<<<B * NH * (S / 8), 256, 0, stream>>>(qkv, y);   // o -> y
        mfma_gemm_kernel<0, true><<<dim3(D / 128, T / 128), 256, 0, stream>>>(
            y, out_w + (size_t)l * D * D, out_b + (size_t)l * D, h, h, T, D, D);
        ln512_kernel<<<T, 256, 0, stream>>>(h, ln2_w + l * D, ln2_b + l * D, y);
        mfma_gemm_kernel<1, false><<<dim3(FF / 128, T / 128), 256, 0, stream>>>(
            y, ff1_w + (size_t)l * FF * D, ff1_b + (size_t)l * FF, nullptr, ff, T, FF, D);
        mfma_gemm_kernel<0, true><<<dim3(D / 128, T / 128), 256, 0, stream>>>(
            ff, ff2_w + (size_t)l * D * FF, ff2_b + (size_t)l * D, h, h, T, D, FF);
    }
    ln512_kernel<<<T, 256, 0, stream>>>(h, fln_w, fln_b, y);
    logpool_kernel<<<(B * D) / 256, 256, 0, stream>>>(y, lp);

    // ---- graph: node encode (LN -> bucket -> typed MFMA GEMM) ----
    node_ln_kernel<<<(NN + 3) / 4, 256, 0, stream>>>(x, node_type, gln_w, gln_b, xab);
    hipMemsetAsync(tcur, 0, 3 * sizeof(int), stream);
    bucket_kernel<<<(NN + 255) / 256, 256, 0, stream>>>(node_type, tcur, perm);
    type_gemm_kernel<<<dim3(2, NPAD / 128, 3), 256, 0, stream>>>(xab, perm, tcur, gw, gb, temb, g_bf);

    // ---- CSR build ----
    hipMemsetAsync(deg_i, 0, NN * sizeof(int), stream);
    hist_kernel<<<(EE + 255) / 256, 256, 0, stream>>>(e_dst, deg_i);
    scan_kernel<<<1, 256, 0, stream>>>(deg_i, row_start, cursor);
    fill_kernel<<<(EE + 255) / 256, 256, 0, stream>>>(e_src, e_dst, cursor, csr_src);

    // ---- 2 SAGE layers ----
    for (int l = 0; l < 2; l++) {
        gather_mean_kernel<<<NN / 2, 256, 0, stream>>>((const unsigned int*)g_bf, csr_src, row_start,
                                                       (unsigned int*)agg_bf);
        sage_mfma_kernel<<<dim3(2, NPAD / 128), 256, 0, stream>>>(agg_bf, g_bf,
            sage_wl + (size_t)l * HG * HG, sage_wr + (size_t)l * HG * HG, sage_bl + (size_t)l * HG, pre);
        ln_relu_kernel<<<NN, 256, 0, stream>>>(pre, g_bf,
            gnorm_w + (size_t)l * HG, gnorm_b + (size_t)l * HG);
    }
    hipMemsetAsync(psum, 0, HG * sizeof(float), stream);
    gpool_kernel<<<256, 256, 0, stream>>>(g_bf, psum);
    fusion_kernel<<<B, 256, 0, stream>>>(lp, psum, fusion_w, fusion_b, fusion_lnw, fusion_lnb,
                                         (float*)d_out);
}

// Round 6
// 1873.805 us; speedup vs baseline: 6.4109x; 1.2488x over previous
//
#include <hip/hip_runtime.h>
#include <hip/hip_bf16.h>
#include <math.h>

#define DEVINL __device__ __forceinline__

constexpr int L = 4, D = 512, FF = 2048, NH = 8, DH = 64, B = 8, S = 512;
constexpr int NN = 50000, EE = 800000, HG = 256, FUS = 768;
constexpr int T = B * S;     // 4096 tokens
constexpr int NPAD = 50048;  // 391 * 128

typedef __attribute__((ext_vector_type(8))) short short8;
typedef __attribute__((ext_vector_type(8))) unsigned short ushort8;
typedef __attribute__((ext_vector_type(4))) float floatx4;

DEVINL float waveRed(float v) { for (int o = 32; o; o >>= 1) v += __shfl_down(v, o); return v; }

DEVINL float ubf(unsigned int u) { union { unsigned int i; float f; } c; c.i = u << 16; return c.f; }
DEVINL unsigned short f2bf(float f) {
    union { float f; unsigned int u; } c; c.f = f;
    unsigned int r = c.u + 0x7fffu + ((c.u >> 16) & 1u);   // RNE
    return (unsigned short)(r >> 16);
}
DEVINL ushort8 pack8(floatx4 x, floatx4 y) {
    ushort8 r;
    r[0] = f2bf(x[0]); r[1] = f2bf(x[1]); r[2] = f2bf(x[2]); r[3] = f2bf(x[3]);
    r[4] = f2bf(y[0]); r[5] = f2bf(y[1]); r[6] = f2bf(y[2]); r[7] = f2bf(y[3]);
    return r;
}

// ---------------- K1: embedding + sinusoidal PE -> h (f32) ----------------
__global__ __launch_bounds__(256) void embed_kernel(const float* __restrict__ tok,
                                                    const int* __restrict__ ids, float* __restrict__ h) {
    int t = blockIdx.x;
    int s = t & (S - 1);
    int id = ids[t];
    const float scale = 22.62741699796952f;               // sqrt(512)
    const float kln = 9.210340371976184f / 512.0f;        // ln(10000)/D
    for (int d = threadIdx.x; d < D; d += 256) {
        float e = tok[(size_t)id * D + d] * scale;
        float ang = (float)s * expf(-(float)(2 * (d >> 1)) * kln);
        float pe = (d & 1) ? cosf(ang) : sinf(ang);
        h[(size_t)t * D + d] = e + pe;
    }
}

// ---------------- K2: LayerNorm over D=512 ----------------
__global__ __launch_bounds__(256) void ln512_kernel(const float* __restrict__ in,
                                                    const float* __restrict__ w,
                                                    const float* __restrict__ bb,
                                                    float* __restrict__ out) {
    int t = blockIdx.x, tid = threadIdx.x;
    const float* row = in + (size_t)t * 512;
    float v0 = row[tid], v1 = row[tid + 256];
    float s1 = waveRed(v0 + v1);
    float s2 = waveRed(v0 * v0 + v1 * v1);
    __shared__ float p1[4], p2[4];
    if ((tid & 63) == 0) { p1[tid >> 6] = s1; p2[tid >> 6] = s2; }
    __syncthreads();
    float S1 = p1[0] + p1[1] + p1[2] + p1[3];
    float S2 = p2[0] + p2[1] + p2[2] + p2[3];
    float mu = S1 / 512.0f, var = S2 / 512.0f - mu * mu;
    float rs = rsqrtf(fmaxf(var, 0.0f) + 1e-5f);
    out[(size_t)t * 512 + tid]       = (v0 - mu) * rs * w[tid]       + bb[tid];
    out[(size_t)t * 512 + tid + 256] = (v1 - mu) * rs * w[tid + 256] + bb[tid + 256];
}

// ---------------- K3: bf16 MFMA GEMM  C[M,N] = act(A[M,K] @ W[N,K]^T + bias (+res)) ----------------
template <int ACT, bool RES>
__global__ __launch_bounds__(256) void mfma_gemm_kernel(const float* __restrict__ A,
                                                        const float* __restrict__ W,
                                                        const float* __restrict__ bias,
                                                        const float* __restrict__ res,
                                                        float* __restrict__ C, int M, int Nn, int K) {
    constexpr int LDH = 40;
    __shared__ unsigned short As[128 * LDH];
    __shared__ unsigned short Ws[128 * LDH];
    const int bm = blockIdx.y * 128, bn = blockIdx.x * 128;
    const int tid = threadIdx.x;
    const int lane = tid & 63, wave = tid >> 6;
    const int wm = (wave & 1) * 64, wn = (wave >> 1) * 64;
    const int fr = lane & 15, fq = lane >> 4;
    floatx4 acc[4][4] = {};
    const int srow = tid >> 1, shalf = (tid & 1) * 16;
    const float* aG = &A[(size_t)(bm + srow) * K + shalf];
    const float* wG = &W[(size_t)(bn + srow) * K + shalf];
    unsigned short* aS = &As[srow * LDH + shalf];
    unsigned short* wS = &Ws[srow * LDH + shalf];
    for (int k0 = 0; k0 < K; k0 += 32) {
        floatx4 a0 = *(const floatx4*)(aG + k0);
        floatx4 a1 = *(const floatx4*)(aG + k0 + 4);
        floatx4 a2 = *(const floatx4*)(aG + k0 + 8);
        floatx4 a3 = *(const floatx4*)(aG + k0 + 12);
        floatx4 w0 = *(const floatx4*)(wG + k0);
        floatx4 w1 = *(const floatx4*)(wG + k0 + 4);
        floatx4 w2 = *(const floatx4*)(wG + k0 + 8);
        floatx4 w3 = *(const floatx4*)(wG + k0 + 12);
        __syncthreads();
        *(ushort8*)(aS)     = pack8(a0, a1);
        *(ushort8*)(aS + 8) = pack8(a2, a3);
        *(ushort8*)(wS)     = pack8(w0, w1);
        *(ushort8*)(wS + 8) = pack8(w2, w3);
        __syncthreads();
        short8 af[4], bfr[4];
#pragma unroll
        for (int i = 0; i < 4; i++) {
            af[i]  = *(const short8*)&As[(wm + i * 16 + fr) * LDH + fq * 8];
            bfr[i] = *(const short8*)&Ws[(wn + i * 16 + fr) * LDH + fq * 8];
        }
#pragma unroll
        for (int mi = 0; mi < 4; mi++)
#pragma unroll
            for (int ni = 0; ni < 4; ni++)
                acc[mi][ni] = __builtin_amdgcn_mfma_f32_16x16x32_bf16(af[mi], bfr[ni], acc[mi][ni], 0, 0, 0);
    }
#pragma unroll
    for (int mi = 0; mi < 4; mi++) {
#pragma unroll
        for (int r = 0; r < 4; r++) {
            int row = bm + wm + mi * 16 + fq * 4 + r;
#pragma unroll
            for (int ni = 0; ni < 4; ni++) {
                int col = bn + wn + ni * 16 + fr;
                float v = acc[mi][ni][r] + bias[col];
                if (RES) v += res[(size_t)row * Nn + col];
                if (ACT == 1) v = 0.5f * v * (1.0f + erff(v * 0.70710678118654752f));
                C[(size_t)row * Nn + col] = v;
            }
        }
    }
}

// ---------------- K3q: QKV GEMM with bf16 split-store epilogue ----------------
// C[token, col] -> q_bf[bh][s][64], k_bf[bh][s][64], v_bf[bh][d][512] (v transposed).
__global__ __launch_bounds__(256) void qkv_gemm_kernel(const float* __restrict__ A,
                                                       const float* __restrict__ W,
                                                       const float* __restrict__ bias,
                                                       unsigned short* __restrict__ qb,
                                                       unsigned short* __restrict__ kb,
                                                       unsigned short* __restrict__ vb) {
    constexpr int LDH = 40, K = 512, Nn = 1536;
    __shared__ unsigned short As[128 * LDH];
    __shared__ unsigned short Ws[128 * LDH];
    const int bm = blockIdx.y * 128, bn = blockIdx.x * 128;
    const int tid = threadIdx.x;
    const int lane = tid & 63, wave = tid >> 6;
    const int wm = (wave & 1) * 64, wn = (wave >> 1) * 64;
    const int fr = lane & 15, fq = lane >> 4;
    floatx4 acc[4][4] = {};
    const int srow = tid >> 1, shalf = (tid & 1) * 16;
    const float* aG = &A[(size_t)(bm + srow) * K + shalf];
    const float* wG = &W[(size_t)(bn + srow) * K + shalf];
    unsigned short* aS = &As[srow * LDH + shalf];
    unsigned short* wS = &Ws[srow * LDH + shalf];
    for (int k0 = 0; k0 < K; k0 += 32) {
        floatx4 a0 = *(const floatx4*)(aG + k0);
        floatx4 a1 = *(const floatx4*)(aG + k0 + 4);
        floatx4 a2 = *(const floatx4*)(aG + k0 + 8);
        floatx4 a3 = *(const floatx4*)(aG + k0 + 12);
        floatx4 w0 = *(const floatx4*)(wG + k0);
        floatx4 w1 = *(const floatx4*)(wG + k0 + 4);
        floatx4 w2 = *(const floatx4*)(wG + k0 + 8);
        floatx4 w3 = *(const floatx4*)(wG + k0 + 12);
        __syncthreads();
        *(ushort8*)(aS)     = pack8(a0, a1);
        *(ushort8*)(aS + 8) = pack8(a2, a3);
        *(ushort8*)(wS)     = pack8(w0, w1);
        *(ushort8*)(wS + 8) = pack8(w2, w3);
        __syncthreads();
        short8 af[4], bfr[4];
#pragma unroll
        for (int i = 0; i < 4; i++) {
            af[i]  = *(const short8*)&As[(wm + i * 16 + fr) * LDH + fq * 8];
            bfr[i] = *(const short8*)&Ws[(wn + i * 16 + fr) * LDH + fq * 8];
        }
#pragma unroll
        for (int mi = 0; mi < 4; mi++)
#pragma unroll
            for (int ni = 0; ni < 4; ni++)
                acc[mi][ni] = __builtin_amdgcn_mfma_f32_16x16x32_bf16(af[mi], bfr[ni], acc[mi][ni], 0, 0, 0);
    }
#pragma unroll
    for (int mi = 0; mi < 4; mi++) {
#pragma unroll
        for (int r = 0; r < 4; r++) {
            int row = bm + wm + mi * 16 + fq * 4 + r;
            int b2 = row >> 9, s2 = row & 511;
#pragma unroll
            for (int ni = 0; ni < 4; ni++) {
                int col = bn + wn + ni * 16 + fr;
                unsigned short val = f2bf(acc[mi][ni][r] + bias[col]);
                int sect = col >> 9, hd = (col >> 6) & 7, d = col & 63;
                size_t bh = (size_t)(b2 * 8 + hd);
                if (sect == 0)      qb[(bh * 512 + s2) * 64 + d] = val;
                else if (sect == 1) kb[(bh * 512 + s2) * 64 + d] = val;
                else                vb[(bh * 64 + d) * 512 + s2] = val;
            }
        }
    }
}

// ---------------- K4: MFMA attention. 1024 blocks = B*NH*(S/32); 2 waves, 16 q/wave ----------------
__global__ __launch_bounds__(128) void attn_mfma_kernel(const unsigned short* __restrict__ qb,
                                                        const unsigned short* __restrict__ kb,
                                                        const unsigned short* __restrict__ vb,
                                                        float* __restrict__ o) {
    constexpr int SP = 520;                 // padded row length (halfwords)
    __shared__ unsigned short sp[2][16 * SP];
    const int blk = blockIdx.x;
    const int qt = blk & 15;                // which 32-query tile
    const int bh = blk >> 4;                // 0..63
    const int tid = threadIdx.x;
    const int lane = tid & 63, wave = tid >> 6;
    const int fr = lane & 15, fq = lane >> 4;
    const int q0 = qt * 32 + wave * 16;     // this wave's first query
    // Q A-fragments (rows q0+fr, k = d)
    const unsigned short* qrow = &qb[((size_t)bh * 512 + q0 + fr) * 64];
    short8 aq0 = *(const short8*)(qrow + fq * 8);
    short8 aq1 = *(const short8*)(qrow + 32 + fq * 8);
    // QK^T: 32 key tiles
    floatx4 sc[32];
#pragma unroll
    for (int t = 0; t < 32; t++) {
        const unsigned short* krow = &kb[((size_t)bh * 512 + t * 16 + fr) * 64];
        short8 bk0 = *(const short8*)(krow + fq * 8);
        short8 bk1 = *(const short8*)(krow + 32 + fq * 8);
        floatx4 a = {};
        a = __builtin_amdgcn_mfma_f32_16x16x32_bf16(aq0, bk0, a, 0, 0, 0);
        a = __builtin_amdgcn_mfma_f32_16x16x32_bf16(aq1, bk1, a, 0, 0, 0);
        sc[t] = a;
    }
    // softmax: lane holds rows fq*4+r (r=0..3), col = 16t+fr
    float mr[4], lr[4];
#pragma unroll
    for (int r = 0; r < 4; r++) {
        float m = -1e30f;
#pragma unroll
        for (int t = 0; t < 32; t++) m = fmaxf(m, sc[t][r]);
        for (int ox = 1; ox < 16; ox <<= 1) m = fmaxf(m, __shfl_xor(m, ox));
        mr[r] = m * 0.125f;
    }
#pragma unroll
    for (int r = 0; r < 4; r++) {
        float s = 0.0f;
#pragma unroll
        for (int t = 0; t < 32; t++) {
            float p = expf(sc[t][r] * 0.125f - mr[r]);
            sc[t][r] = p;
            s += p;
        }
        for (int ox = 1; ox < 16; ox <<= 1) s += __shfl_xor(s, ox);
        lr[r] = s;
    }
    // P -> LDS (C-layout scatter, A-layout gather)
    unsigned short* spw = sp[wave];
#pragma unroll
    for (int t = 0; t < 32; t++)
#pragma unroll
        for (int r = 0; r < 4; r++)
            spw[(fq * 4 + r) * SP + t * 16 + fr] = f2bf(sc[t][r]);
    __syncthreads();
    // PV: O[16,64] = P[16,512] @ V^T-frags; A from LDS, B from v_bf[bh][d][s]
    floatx4 oa[4] = {};
#pragma unroll
    for (int kt = 0; kt < 16; kt++) {
        short8 ap = *(const short8*)&spw[fr * SP + kt * 32 + fq * 8];
#pragma unroll
        for (int tn = 0; tn < 4; tn++) {
            const unsigned short* vrow = &vb[((size_t)bh * 64 + tn * 16 + fr) * 512 + kt * 32 + fq * 8];
            short8 bv = *(const short8*)vrow;
            oa[tn] = __builtin_amdgcn_mfma_f32_16x16x32_bf16(ap, bv, oa[tn], 0, 0, 0);
        }
    }
    const int b2 = bh >> 3, h2 = bh & 7;
    float inv[4];
#pragma unroll
    for (int r = 0; r < 4; r++) inv[r] = 1.0f / lr[r];
#pragma unroll
    for (int tn = 0; tn < 4; tn++)
#pragma unroll
        for (int r = 0; r < 4; r++) {
            int row = fq * 4 + r;
            int col = tn * 16 + fr;
            o[((size_t)b2 * 512 + q0 + row) * 512 + h2 * 64 + col] = oa[tn][r] * inv[r];
        }
}

// ---------------- K3b: SAGE MFMA GEMM  pre[N,256] = [agg|g](bf16) @ [wl|wr]^T + bl ----------------
__global__ __launch_bounds__(256) void sage_mfma_kernel(const unsigned short* __restrict__ agg_bf,
                                                        const unsigned short* __restrict__ g_bf,
                                                        const float* __restrict__ wl,
                                                        const float* __restrict__ wr,
                                                        const float* __restrict__ bl,
                                                        float* __restrict__ pre) {
    constexpr int LDH = 40;
    __shared__ unsigned short As[128 * LDH];
    __shared__ unsigned short Ws[128 * LDH];
    const int bm = blockIdx.y * 128, bn = blockIdx.x * 128;
    const int tid = threadIdx.x;
    const int lane = tid & 63, wave = tid >> 6;
    const int wm = (wave & 1) * 64, wn = (wave >> 1) * 64;
    const int fr = lane & 15, fq = lane >> 4;
    floatx4 acc[4][4] = {};
    const int srow = tid >> 1, shalf = (tid & 1) * 16;
    int an = bm + srow; if (an >= NN) an = NN - 1;
    const int outc = bn + srow;
    unsigned short* aS = &As[srow * LDH + shalf];
    unsigned short* wS = &Ws[srow * LDH + shalf];
    for (int k0 = 0; k0 < 512; k0 += 32) {
        int kg = k0 + shalf;
        const unsigned short* asrc = (kg < 256) ? &agg_bf[(size_t)an * 256 + kg]
                                                : &g_bf[(size_t)an * 256 + (kg - 256)];
        const float* bsrc = (kg < 256) ? &wl[(size_t)outc * 256 + kg]
                                       : &wr[(size_t)outc * 256 + (kg - 256)];
        ushort8 alo = *(const ushort8*)asrc;
        ushort8 ahi = *(const ushort8*)(asrc + 8);
        floatx4 w0 = *(const floatx4*)(bsrc);
        floatx4 w1 = *(const floatx4*)(bsrc + 4);
        floatx4 w2 = *(const floatx4*)(bsrc + 8);
        floatx4 w3 = *(const floatx4*)(bsrc + 12);
        __syncthreads();
        *(ushort8*)(aS)     = alo;
        *(ushort8*)(aS + 8) = ahi;
        *(ushort8*)(wS)     = pack8(w0, w1);
        *(ushort8*)(wS + 8) = pack8(w2, w3);
        __syncthreads();
        short8 af[4], bfr[4];
#pragma unroll
        for (int i = 0; i < 4; i++) {
            af[i]  = *(const short8*)&As[(wm + i * 16 + fr) * LDH + fq * 8];
            bfr[i] = *(const short8*)&Ws[(wn + i * 16 + fr) * LDH + fq * 8];
        }
#pragma unroll
        for (int mi = 0; mi < 4; mi++)
#pragma unroll
            for (int ni = 0; ni < 4; ni++)
                acc[mi][ni] = __builtin_amdgcn_mfma_f32_16x16x32_bf16(af[mi], bfr[ni], acc[mi][ni], 0, 0, 0);
    }
#pragma unroll
    for (int mi = 0; mi < 4; mi++) {
#pragma unroll
        for (int r = 0; r < 4; r++) {
            int row = bm + wm + mi * 16 + fq * 4 + r;
            if (row < NN) {
#pragma unroll
                for (int ni = 0; ni < 4; ni++) {
                    int col = bn + wn + ni * 16 + fr;
                    pre[(size_t)row * 256 + col] = acc[mi][ni][r] + bl[col];
                }
            }
        }
    }
}

// ---------------- K3c: residual + LN(256) + ReLU -> g_bf (in place) ----------------
__global__ __launch_bounds__(256) void ln_relu_kernel(const float* __restrict__ pre,
                                                      unsigned short* __restrict__ g_bf,
                                                      const float* __restrict__ gnw,
                                                      const float* __restrict__ gnb) {
    int n = blockIdx.x, tid = threadIdx.x;
    float res = ubf(g_bf[(size_t)n * 256 + tid]);
    float v = pre[(size_t)n * 256 + tid] + res;
    __shared__ float p1[4], p2[4];
    float s1 = waveRed(v);
    float s2 = waveRed(v * v);
    if ((tid & 63) == 0) { p1[tid >> 6] = s1; p2[tid >> 6] = s2; }
    __syncthreads();
    float S1 = p1[0] + p1[1] + p1[2] + p1[3];
    float S2 = p2[0] + p2[1] + p2[2] + p2[3];
    float mu = S1 / 256.0f, var = S2 / 256.0f - mu * mu;
    float rs = rsqrtf(fmaxf(var, 0.0f) + 1e-5f);
    float r = (v - mu) * rs * gnw[tid] + gnb[tid];
    g_bf[(size_t)n * 256 + tid] = f2bf(fmaxf(r, 0.0f));
}

// ---------------- K5: masked mean pool over S ----------------
__global__ __launch_bounds__(256) void logpool_kernel(const float* __restrict__ hf, float* __restrict__ lp) {
    int idx = blockIdx.x * 256 + threadIdx.x;
    int b = idx >> 9, d = idx & 511;
    float s = 0.0f;
    for (int t = 0; t < 512; t++) s += hf[(size_t)(b * 512 + t) * 512 + d];
    lp[idx] = s * (1.0f / 512.0f);
}

// ---------------- K6a: node clip + shared LN + per-type affine -> xab bf16 [n][64] ----------------
__global__ __launch_bounds__(256) void node_ln_kernel(const float* __restrict__ x,
                                                      const int* __restrict__ ntype,
                                                      const float* __restrict__ glnw,
                                                      const float* __restrict__ glnb,
                                                      unsigned short* __restrict__ xab) {
    int tid = threadIdx.x;
    int n = blockIdx.x * 4 + (tid >> 6);
    int lane = tid & 63;
    if (n >= NN) return;
    float v = x[(size_t)n * 64 + lane];
    v = fminf(10.0f, fmaxf(-10.0f, v));
    float s1 = waveRed(v);        s1 = __shfl(s1, 0);
    float s2 = waveRed(v * v);    s2 = __shfl(s2, 0);
    float mu = s1 / 64.0f, var = s2 / 64.0f - mu * mu;
    float rs = rsqrtf(fmaxf(var, 0.0f) + 1e-5f);
    int t = ntype[n];
    float r = (v - mu) * rs * glnw[t * 64 + lane] + glnb[t * 64 + lane];
    xab[(size_t)n * 64 + lane] = f2bf(r);
}

// ---------------- K6b: bucket nodes by type (LDS-aggregated) ----------------
__global__ __launch_bounds__(256) void bucket_kernel(const int* __restrict__ ntype,
                                                     int* __restrict__ tcur,
                                                     int* __restrict__ perm) {
    __shared__ int lcnt[3], lbase[3];
    int tid = threadIdx.x;
    int n = blockIdx.x * 256 + tid;
    if (tid < 3) lcnt[tid] = 0;
    __syncthreads();
    int t = 0, lpos = 0;
    bool act = (n < NN);
    if (act) { t = ntype[n]; lpos = atomicAdd(&lcnt[t], 1); }
    __syncthreads();
    if (tid < 3) lbase[tid] = atomicAdd(&tcur[tid], lcnt[tid]);
    __syncthreads();
    if (act) perm[t * NPAD + lbase[t] + lpos] = n;
}

// ---------------- K6c: per-type MFMA GEMM ----------------
__global__ __launch_bounds__(256) void type_gemm_kernel(const unsigned short* __restrict__ xab,
                                                        const int* __restrict__ perm,
                                                        const int* __restrict__ cnts,
                                                        const float* __restrict__ gw,
                                                        const float* __restrict__ gb,
                                                        const float* __restrict__ temb,
                                                        unsigned short* __restrict__ g_bf) {
    constexpr int LDH = 40;
    __shared__ unsigned short As[128 * LDH];
    __shared__ unsigned short Ws[128 * LDH];
    const int t = blockIdx.z;
    const int cnt = cnts[t];
    const int bm = blockIdx.y * 128, bn = blockIdx.x * 128;
    if (bm >= cnt) return;
    const int tid = threadIdx.x;
    const int lane = tid & 63, wave = tid >> 6;
    const int wm = (wave & 1) * 64, wn = (wave >> 1) * 64;
    const int fr = lane & 15, fq = lane >> 4;
    floatx4 acc[4][4] = {};
    const int srow = tid >> 1, shalf = (tid & 1) * 16;
    int gr = bm + srow; if (gr >= cnt) gr = cnt - 1;
    const int node = perm[t * NPAD + gr];
    const int outc = bn + srow;
    unsigned short* aS = &As[srow * LDH + shalf];
    unsigned short* wS = &Ws[srow * LDH + shalf];
#pragma unroll
    for (int k0 = 0; k0 < 64; k0 += 32) {
        const unsigned short* asrc = &xab[(size_t)node * 64 + k0 + shalf];
        const float* bsrc = &gw[((size_t)t * 256 + outc) * 64 + k0 + shalf];
        ushort8 alo = *(const ushort8*)asrc;
        ushort8 ahi = *(const ushort8*)(asrc + 8);
        floatx4 w0 = *(const floatx4*)(bsrc);
        floatx4 w1 = *(const floatx4*)(bsrc + 4);
        floatx4 w2 = *(const floatx4*)(bsrc + 8);
        floatx4 w3 = *(const floatx4*)(bsrc + 12);
        __syncthreads();
        *(ushort8*)(aS)     = alo;
        *(ushort8*)(aS + 8) = ahi;
        *(ushort8*)(wS)     = pack8(w0, w1);
        *(ushort8*)(wS + 8) = pack8(w2, w3);
        __syncthreads();
        short8 af[4], bfr[4];
#pragma unroll
        for (int i = 0; i < 4; i++) {
            af[i]  = *(const short8*)&As[(wm + i * 16 + fr) * LDH + fq * 8];
            bfr[i] = *(const short8*)&Ws[(wn + i * 16 + fr) * LDH + fq * 8];
        }
#pragma unroll
        for (int mi = 0; mi < 4; mi++)
#pragma unroll
            for (int ni = 0; ni < 4; ni++)
                acc[mi][ni] = __builtin_amdgcn_mfma_f32_16x16x32_bf16(af[mi], bfr[ni], acc[mi][ni], 0, 0, 0);
    }
#pragma unroll
    for (int mi = 0; mi < 4; mi++) {
#pragma unroll
        for (int r = 0; r < 4; r++) {
            int row = bm + wm + mi * 16 + fq * 4 + r;
            if (row < cnt) {
                int nd = perm[t * NPAD + row];
#pragma unroll
                for (int ni = 0; ni < 4; ni++) {
                    int col = bn + wn + ni * 16 + fr;
                    g_bf[(size_t)nd * 256 + col] =
                        f2bf(acc[mi][ni][r] + gb[t * 256 + col] + temb[t * 256 + col]);
                }
            }
        }
    }
}

// ---------------- CSR build ----------------
__global__ __launch_bounds__(256) void hist_kernel(const int* __restrict__ dst, int* __restrict__ deg) {
    int e = blockIdx.x * 256 + threadIdx.x;
    if (e < EE) atomicAdd(&deg[dst[e]], 1);
}

__global__ __launch_bounds__(256) void scan_kernel(const int* __restrict__ deg,
                                                   int* __restrict__ row_start,
                                                   int* __restrict__ cursor) {
    constexpr int CH = (NN + 255) / 256;
    int tid = threadIdx.x;
    __shared__ int part[256];
    int begin = tid * CH;
    int sum = 0;
    for (int i = 0; i < CH; i++) { int idx = begin + i; if (idx < NN) sum += deg[idx]; }
    part[tid] = sum;
    __syncthreads();
    for (int off = 1; off < 256; off <<= 1) {
        int t = (tid >= off) ? part[tid - off] : 0;
        __syncthreads();
        part[tid] += t;
        __syncthreads();
    }
    int run = part[tid] - sum;
    for (int i = 0; i < CH; i++) {
        int idx = begin + i;
        if (idx < NN) {
            row_start[idx] = run; cursor[idx] = run;
            run += deg[idx];
        }
    }
    if (tid == 255) row_start[NN] = run;
}

__global__ __launch_bounds__(256) void fill_kernel(const int* __restrict__ src,
                                                   const int* __restrict__ dst,
                                                   int* __restrict__ cursor,
                                                   int* __restrict__ csr_src) {
    int e = blockIdx.x * 256 + threadIdx.x;
    if (e < EE) {
        int pos = atomicAdd(&cursor[dst[e]], 1);
        csr_src[pos] = src[e];
    }
}

// ---------------- K8: gather-mean (2 nodes/block, bf16-pair/thread, 4-deep MLP) ----------------
__global__ __launch_bounds__(256) void gather_mean_kernel(const unsigned int* __restrict__ g32,
                                                          const int* __restrict__ csr_src,
                                                          const int* __restrict__ row_start,
                                                          unsigned int* __restrict__ agg32) {
    int tid = threadIdx.x;
    int n = blockIdx.x * 2 + (tid >> 7);
    int c = tid & 127;
    int beg = row_start[n], end = row_start[n + 1];
    float a0 = 0, a1 = 0, a2 = 0, a3 = 0;
    float b0 = 0, b1 = 0, b2 = 0, b3 = 0;
    int i = beg;
    for (; i + 4 <= end; i += 4) {
        int s0 = csr_src[i], s1 = csr_src[i + 1], s2 = csr_src[i + 2], s3 = csr_src[i + 3];
        unsigned int u0 = g32[(size_t)s0 * 128 + c];
        unsigned int u1 = g32[(size_t)s1 * 128 + c];
        unsigned int u2 = g32[(size_t)s2 * 128 + c];
        unsigned int u3 = g32[(size_t)s3 * 128 + c];
        a0 += ubf(u0 & 0xffff); b0 += ubf(u0 >> 16);
        a1 += ubf(u1 & 0xffff); b1 += ubf(u1 >> 16);
        a2 += ubf(u2 & 0xffff); b2 += ubf(u2 >> 16);
        a3 += ubf(u3 & 0xffff); b3 += ubf(u3 >> 16);
    }
    for (; i < end; i++) {
        int s = csr_src[i];
        unsigned int u = g32[(size_t)s * 128 + c];
        a0 += ubf(u & 0xffff); b0 += ubf(u >> 16);
    }
    float den = (end > beg) ? (float)(end - beg) : 1.0f;
    float m0 = ((a0 + a1) + (a2 + a3)) / den;
    float m1 = ((b0 + b1) + (b2 + b3)) / den;
    agg32[(size_t)n * 128 + c] = (unsigned int)f2bf(m0) | ((unsigned int)f2bf(m1) << 16);
}

// ---------------- K11: column mean over N nodes ----------------
__global__ __launch_bounds__(256) void gpool_kernel(const unsigned short* __restrict__ g_bf,
                                                    float* __restrict__ psum) {
    int tid = threadIdx.x, blk = blockIdx.x;
    float acc = 0.0f;
    for (int n = blk; n < NN; n += 256) acc += ubf(g_bf[(size_t)n * 256 + tid]);
    atomicAdd(&psum[tid], acc);
}

// ---------------- K12: fusion linear + LN + ReLU -> f32 out ----------------
__global__ __launch_bounds__(256) void fusion_kernel(const float* __restrict__ lp,
                                                     const float* __restrict__ psum,
                                                     const float* __restrict__ fw,
                                                     const float* __restrict__ fb,
                                                     const float* __restrict__ flnw,
                                                     const float* __restrict__ flnb,
                                                     float* __restrict__ out) {
    int b = blockIdx.x, tid = threadIdx.x;
    __shared__ float fin[768], fo[768];
    __shared__ float p1[4], p2[4];
    for (int i = tid; i < 512; i += 256) fin[i] = lp[b * 512 + i];
    if (tid < 256) fin[512 + tid] = psum[tid] * (1.0f / 50000.0f);
    __syncthreads();
    for (int j = tid; j < 768; j += 256) {
        float acc = fb[j];
        const float4* w4 = (const float4*)(fw + (size_t)j * 768);
#pragma unroll 4
        for (int i4 = 0; i4 < 192; i4++) {
            float4 u = w4[i4];
            acc += fin[4 * i4 + 0] * u.x + fin[4 * i4 + 1] * u.y
                 + fin[4 * i4 + 2] * u.z + fin[4 * i4 + 3] * u.w;
        }
        fo[j] = acc;
    }
    __syncthreads();
    float s1 = 0.0f, s2 = 0.0f;
    for (int j = tid; j < 768; j += 256) { float vv = fo[j]; s1 += vv; s2 += vv * vv; }
    s1 = waveRed(s1); s2 = waveRed(s2);
    if ((tid & 63) == 0) { p1[tid >> 6] = s1; p2[tid >> 6] = s2; }
    __syncthreads();
    float S1 = p1[0] + p1[1] + p1[2] + p1[3];
    float S2 = p2[0] + p2[1] + p2[2] + p2[3];
    float mu = S1 / 768.0f, var = S2 / 768.0f - mu * mu;
    float rs = rsqrtf(fmaxf(var, 0.0f) + 1e-5f);
    for (int j = tid; j < 768; j += 256) {
        float r = (fo[j] - mu) * rs * flnw[j] + flnb[j];
        out[b * 768 + j] = fmaxf(r, 0.0f);
    }
}

extern "C" void kernel_launch(void* const* d_in, const int* in_sizes, int n_in,
                              void* d_out, int out_size, void* d_ws, size_t ws_size,
                              hipStream_t stream) {
    (void)in_sizes; (void)n_in; (void)out_size; (void)ws_size;
    const float* tok_emb = (const float*)d_in[0];
    const float* qkv_w   = (const float*)d_in[1];
    const float* qkv_b   = (const float*)d_in[2];
    const float* out_w   = (const float*)d_in[3];
    const float* out_b   = (const float*)d_in[4];
    const float* ln1_w   = (const float*)d_in[5];
    const float* ln1_b   = (const float*)d_in[6];
    const float* ln2_w   = (const float*)d_in[7];
    const float* ln2_b   = (const float*)d_in[8];
    const float* ff1_w   = (const float*)d_in[9];
    const float* ff1_b   = (const float*)d_in[10];
    const float* ff2_w   = (const float*)d_in[11];
    const float* ff2_b   = (const float*)d_in[12];
    const float* fln_w   = (const float*)d_in[13];
    const float* fln_b   = (const float*)d_in[14];
    const float* x       = (const float*)d_in[15];
    const float* gln_w   = (const float*)d_in[16];
    const float* gln_b   = (const float*)d_in[17];
    const float* gw      = (const float*)d_in[18];
    const float* gb      = (const float*)d_in[19];
    const float* temb    = (const float*)d_in[20];
    const float* sage_wl = (const float*)d_in[21];
    const float* sage_bl = (const float*)d_in[22];
    const float* sage_wr = (const float*)d_in[23];
    const float* gnorm_w = (const float*)d_in[24];
    const float* gnorm_b = (const float*)d_in[25];
    const float* fusion_w   = (const float*)d_in[26];
    const float* fusion_b   = (const float*)d_in[27];
    const float* fusion_lnw = (const float*)d_in[28];
    const float* fusion_lnb = (const float*)d_in[29];
    const int* input_ids  = (const int*)d_in[30];
    // d_in[31] = attention_mask: all-true, unused
    const int* edge_index = (const int*)d_in[32];
    const int* node_type  = (const int*)d_in[33];
    const int* e_src = edge_index;
    const int* e_dst = edge_index + EE;

    // workspace layout (float units)
    float* ws  = (float*)d_ws;
    float* h   = ws;                      // 2,097,152
    float* y   = ws + 2097152;            // 2,097,152
    float* ff  = ws + 4194304;            // 8,388,608 floats (region A, ends 12,582,912)
    unsigned short* xab = (unsigned short*)ws;            // graph phase (aliases h/y)
    int* perm  = (int*)(ws + 1601536);
    int* tcur  = (int*)(ws + 1751680);
    float* pre = ws;                      // NPAD*256 floats (sage phase, aliases region A)
    // q/k/v bf16 alias the g_bf region (graph phase starts after transformer)
    unsigned short* q_bf = (unsigned short*)(ws + 12812288);      // 2,097,152 ushorts
    unsigned short* k_bf = q_bf + 2097152;
    unsigned short* v_bf = q_bf + 4194304;                        // ends at float ofs 15,958,016
    unsigned short* g_bf   = (unsigned short*)(ws + 12812288);    // 50048*256 ushorts (graph phase)
    unsigned short* agg_bf = (unsigned short*)(ws + 19218432);
    float* lp   = ws + 25624576;          // 4096
    float* psum = ws + 25628672;          // 256
    int* ibase     = (int*)(ws + 25628928);
    int* deg_i     = ibase;               // 50,000
    int* row_start = ibase + 50000;       // 50,001
    int* cursor    = ibase + 100001;      // 50,000
    int* csr_src   = ibase + 150001;      // 800,000
    // total: 26,578,929 floats = 106.3 MB

    // ---- transformer ----
    embed_kernel<<<T, 256, 0, stream>>>(tok_emb, input_ids, h);
    for (int l = 0; l < L; l++) {
        ln512_kernel<<<T, 256, 0, stream>>>(h, ln1_w + l * D, ln1_b + l * D, y);
        qkv_gemm_kernel<<<dim3(12, 32), 256, 0, stream>>>(
            y, qkv_w + (size_t)l * 3 * D * D, qkv_b + (size_t)l * 3 * D, q_bf, k_bf, v_bf);
        attn_mfma_kernel<<<B * NH * (S / 32), 128, 0, stream>>>(q_bf, k_bf, v_bf, y);
        mfma_gemm_kernel<0, true><<<dim3(D / 128, T / 128), 256, 0, stream>>>(
            y, out_w + (size_t)l * D * D, out_b + (size_t)l * D, h, h, T, D, D);
        ln512_kernel<<<T, 256, 0, stream>>>(h, ln2_w + l * D, ln2_b + l * D, y);
        mfma_gemm_kernel<1, false><<<dim3(FF / 128, T / 128), 256, 0, stream>>>(
            y, ff1_w + (size_t)l * FF * D, ff1_b + (size_t)l * FF, nullptr, ff, T, FF, D);
        mfma_gemm_kernel<0, true><<<dim3(D / 128, T / 128), 256, 0, stream>>>(
            ff, ff2_w + (size_t)l * D * FF, ff2_b + (size_t)l * D, h, h, T, D, FF);
    }
    ln512_kernel<<<T, 256, 0, stream>>>(h, fln_w, fln_b, y);
    logpool_kernel<<<(B * D) / 256, 256, 0, stream>>>(y, lp);

    // ---- graph: node encode (LN -> bucket -> typed MFMA GEMM) ----
    node_ln_kernel<<<(NN + 3) / 4, 256, 0, stream>>>(x, node_type, gln_w, gln_b, xab);
    hipMemsetAsync(tcur, 0, 3 * sizeof(int), stream);
    bucket_kernel<<<(NN + 255) / 256, 256, 0, stream>>>(node_type, tcur, perm);
    type_gemm_kernel<<<dim3(2, NPAD / 128, 3), 256, 0, stream>>>(xab, perm, tcur, gw, gb, temb, g_bf);

    // ---- CSR build ----
    hipMemsetAsync(deg_i, 0, NN * sizeof(int), stream);
    hist_kernel<<<(EE + 255) / 256, 256, 0, stream>>>(e_dst, deg_i);
    scan_kernel<<<1, 256, 0, stream>>>(deg_i, row_start, cursor);
    fill_kernel<<<(EE + 255) / 256, 256, 0, stream>>>(e_src, e_dst, cursor, csr_src);

    // ---- 2 SAGE layers ----
    for (int l = 0; l < 2; l++) {
        gather_mean_kernel<<<NN / 2, 256, 0, stream>>>((const unsigned int*)g_bf, csr_src, row_start,
                                                       (unsigned int*)agg_bf);
        sage_mfma_kernel<<<dim3(2, NPAD / 128), 256, 0, stream>>>(agg_bf, g_bf,
            sage_wl + (size_t)l * HG * HG, sage_wr + (size_t)l * HG * HG, sage_bl + (size_t)l * HG, pre);
        ln_relu_kernel<<<NN, 256, 0, stream>>>(pre, g_bf,
            gnorm_w + (size_t)l * HG, gnorm_b + (size_t)l * HG);
    }
    hipMemsetAsync(psum, 0, HG * sizeof(float), stream);
    gpool_kernel<<<256, 256, 0, stream>>>(g_bf, psum);
    fusion_kernel<<<B, 256, 0, stream>>>(lp, psum, fusion_w, fusion_b, fusion_lnw, fusion_lnb,
                                         (float*)d_out);
}

// Round 7
// 1745.739 us; speedup vs baseline: 6.8812x; 1.0734x over previous
//
#include <hip/hip_runtime.h>
#include <hip/hip_bf16.h>
#include <math.h>

#define DEVINL __device__ __forceinline__

constexpr int L = 4, D = 512, FF = 2048, NH = 8, DH = 64, B = 8, S = 512;
constexpr int NN = 50000, EE = 800000, HG = 256, FUS = 768;
constexpr int T = B * S;     // 4096 tokens
constexpr int NPAD = 50048;  // 391 * 128
constexpr int NB = (NN + 255) / 256;   // 196 scan blocks

typedef __attribute__((ext_vector_type(8))) short short8;
typedef __attribute__((ext_vector_type(8))) unsigned short ushort8;
typedef __attribute__((ext_vector_type(4))) float floatx4;

DEVINL float waveRed(float v) { for (int o = 32; o; o >>= 1) v += __shfl_down(v, o); return v; }

DEVINL float ubf(unsigned int u) { union { unsigned int i; float f; } c; c.i = u << 16; return c.f; }
DEVINL unsigned short f2bf(float f) {
    union { float f; unsigned int u; } c; c.f = f;
    unsigned int r = c.u + 0x7fffu + ((c.u >> 16) & 1u);   // RNE
    return (unsigned short)(r >> 16);
}
DEVINL ushort8 pack8(floatx4 x, floatx4 y) {
    ushort8 r;
    r[0] = f2bf(x[0]); r[1] = f2bf(x[1]); r[2] = f2bf(x[2]); r[3] = f2bf(x[3]);
    r[4] = f2bf(y[0]); r[5] = f2bf(y[1]); r[6] = f2bf(y[2]); r[7] = f2bf(y[3]);
    return r;
}

// ---------------- K1: embedding + sinusoidal PE -> h (f32) ----------------
__global__ __launch_bounds__(256) void embed_kernel(const float* __restrict__ tok,
                                                    const int* __restrict__ ids, float* __restrict__ h) {
    int t = blockIdx.x;
    int s = t & (S - 1);
    int id = ids[t];
    const float scale = 22.62741699796952f;               // sqrt(512)
    const float kln = 9.210340371976184f / 512.0f;        // ln(10000)/D
    for (int d = threadIdx.x; d < D; d += 256) {
        float e = tok[(size_t)id * D + d] * scale;
        float ang = (float)s * expf(-(float)(2 * (d >> 1)) * kln);
        float pe = (d & 1) ? cosf(ang) : sinf(ang);
        h[(size_t)t * D + d] = e + pe;
    }
}

// ---------------- K2: LayerNorm over D=512 ----------------
__global__ __launch_bounds__(256) void ln512_kernel(const float* __restrict__ in,
                                                    const float* __restrict__ w,
                                                    const float* __restrict__ bb,
                                                    float* __restrict__ out) {
    int t = blockIdx.x, tid = threadIdx.x;
    const float* row = in + (size_t)t * 512;
    float v0 = row[tid], v1 = row[tid + 256];
    float s1 = waveRed(v0 + v1);
    float s2 = waveRed(v0 * v0 + v1 * v1);
    __shared__ float p1[4], p2[4];
    if ((tid & 63) == 0) { p1[tid >> 6] = s1; p2[tid >> 6] = s2; }
    __syncthreads();
    float S1 = p1[0] + p1[1] + p1[2] + p1[3];
    float S2 = p2[0] + p2[1] + p2[2] + p2[3];
    float mu = S1 / 512.0f, var = S2 / 512.0f - mu * mu;
    float rs = rsqrtf(fmaxf(var, 0.0f) + 1e-5f);
    out[(size_t)t * 512 + tid]       = (v0 - mu) * rs * w[tid]       + bb[tid];
    out[(size_t)t * 512 + tid + 256] = (v1 - mu) * rs * w[tid + 256] + bb[tid + 256];
}

// ---------------- K3: bf16 MFMA GEMM  C[M,N] = act(A[M,K] @ W[N,K]^T + bias (+res)) ----------------
template <int ACT, bool RES>
__global__ __launch_bounds__(256) void mfma_gemm_kernel(const float* __restrict__ A,
                                                        const float* __restrict__ W,
                                                        const float* __restrict__ bias,
                                                        const float* __restrict__ res,
                                                        float* __restrict__ C, int M, int Nn, int K) {
    constexpr int LDH = 40;
    __shared__ unsigned short As[128 * LDH];
    __shared__ unsigned short Ws[128 * LDH];
    const int bm = blockIdx.y * 128, bn = blockIdx.x * 128;
    const int tid = threadIdx.x;
    const int lane = tid & 63, wave = tid >> 6;
    const int wm = (wave & 1) * 64, wn = (wave >> 1) * 64;
    const int fr = lane & 15, fq = lane >> 4;
    floatx4 acc[4][4] = {};
    const int srow = tid >> 1, shalf = (tid & 1) * 16;
    const float* aG = &A[(size_t)(bm + srow) * K + shalf];
    const float* wG = &W[(size_t)(bn + srow) * K + shalf];
    unsigned short* aS = &As[srow * LDH + shalf];
    unsigned short* wS = &Ws[srow * LDH + shalf];
    for (int k0 = 0; k0 < K; k0 += 32) {
        floatx4 a0 = *(const floatx4*)(aG + k0);
        floatx4 a1 = *(const floatx4*)(aG + k0 + 4);
        floatx4 a2 = *(const floatx4*)(aG + k0 + 8);
        floatx4 a3 = *(const floatx4*)(aG + k0 + 12);
        floatx4 w0 = *(const floatx4*)(wG + k0);
        floatx4 w1 = *(const floatx4*)(wG + k0 + 4);
        floatx4 w2 = *(const floatx4*)(wG + k0 + 8);
        floatx4 w3 = *(const floatx4*)(wG + k0 + 12);
        __syncthreads();
        *(ushort8*)(aS)     = pack8(a0, a1);
        *(ushort8*)(aS + 8) = pack8(a2, a3);
        *(ushort8*)(wS)     = pack8(w0, w1);
        *(ushort8*)(wS + 8) = pack8(w2, w3);
        __syncthreads();
        short8 af[4], bfr[4];
#pragma unroll
        for (int i = 0; i < 4; i++) {
            af[i]  = *(const short8*)&As[(wm + i * 16 + fr) * LDH + fq * 8];
            bfr[i] = *(const short8*)&Ws[(wn + i * 16 + fr) * LDH + fq * 8];
        }
#pragma unroll
        for (int mi = 0; mi < 4; mi++)
#pragma unroll
            for (int ni = 0; ni < 4; ni++)
                acc[mi][ni] = __builtin_amdgcn_mfma_f32_16x16x32_bf16(af[mi], bfr[ni], acc[mi][ni], 0, 0, 0);
    }
#pragma unroll
    for (int mi = 0; mi < 4; mi++) {
#pragma unroll
        for (int r = 0; r < 4; r++) {
            int row = bm + wm + mi * 16 + fq * 4 + r;
#pragma unroll
            for (int ni = 0; ni < 4; ni++) {
                int col = bn + wn + ni * 16 + fr;
                float v = acc[mi][ni][r] + bias[col];
                if (RES) v += res[(size_t)row * Nn + col];
                if (ACT == 1) v = 0.5f * v * (1.0f + erff(v * 0.70710678118654752f));
                C[(size_t)row * Nn + col] = v;
            }
        }
    }
}

// ---------------- K3q: QKV GEMM with bf16 split-store epilogue ----------------
__global__ __launch_bounds__(256) void qkv_gemm_kernel(const float* __restrict__ A,
                                                       const float* __restrict__ W,
                                                       const float* __restrict__ bias,
                                                       unsigned short* __restrict__ qb,
                                                       unsigned short* __restrict__ kb,
                                                       unsigned short* __restrict__ vb) {
    constexpr int LDH = 40, K = 512;
    __shared__ unsigned short As[128 * LDH];
    __shared__ unsigned short Ws[128 * LDH];
    const int bm = blockIdx.y * 128, bn = blockIdx.x * 128;
    const int tid = threadIdx.x;
    const int lane = tid & 63, wave = tid >> 6;
    const int wm = (wave & 1) * 64, wn = (wave >> 1) * 64;
    const int fr = lane & 15, fq = lane >> 4;
    floatx4 acc[4][4] = {};
    const int srow = tid >> 1, shalf = (tid & 1) * 16;
    const float* aG = &A[(size_t)(bm + srow) * K + shalf];
    const float* wG = &W[(size_t)(bn + srow) * K + shalf];
    unsigned short* aS = &As[srow * LDH + shalf];
    unsigned short* wS = &Ws[srow * LDH + shalf];
    for (int k0 = 0; k0 < K; k0 += 32) {
        floatx4 a0 = *(const floatx4*)(aG + k0);
        floatx4 a1 = *(const floatx4*)(aG + k0 + 4);
        floatx4 a2 = *(const floatx4*)(aG + k0 + 8);
        floatx4 a3 = *(const floatx4*)(aG + k0 + 12);
        floatx4 w0 = *(const floatx4*)(wG + k0);
        floatx4 w1 = *(const floatx4*)(wG + k0 + 4);
        floatx4 w2 = *(const floatx4*)(wG + k0 + 8);
        floatx4 w3 = *(const floatx4*)(wG + k0 + 12);
        __syncthreads();
        *(ushort8*)(aS)     = pack8(a0, a1);
        *(ushort8*)(aS + 8) = pack8(a2, a3);
        *(ushort8*)(wS)     = pack8(w0, w1);
        *(ushort8*)(wS + 8) = pack8(w2, w3);
        __syncthreads();
        short8 af[4], bfr[4];
#pragma unroll
        for (int i = 0; i < 4; i++) {
            af[i]  = *(const short8*)&As[(wm + i * 16 + fr) * LDH + fq * 8];
            bfr[i] = *(const short8*)&Ws[(wn + i * 16 + fr) * LDH + fq * 8];
        }
#pragma unroll
        for (int mi = 0; mi < 4; mi++)
#pragma unroll
            for (int ni = 0; ni < 4; ni++)
                acc[mi][ni] = __builtin_amdgcn_mfma_f32_16x16x32_bf16(af[mi], bfr[ni], acc[mi][ni], 0, 0, 0);
    }
#pragma unroll
    for (int mi = 0; mi < 4; mi++) {
#pragma unroll
        for (int r = 0; r < 4; r++) {
            int row = bm + wm + mi * 16 + fq * 4 + r;
            int b2 = row >> 9, s2 = row & 511;
#pragma unroll
            for (int ni = 0; ni < 4; ni++) {
                int col = bn + wn + ni * 16 + fr;
                unsigned short val = f2bf(acc[mi][ni][r] + bias[col]);
                int sect = col >> 9, hd = (col >> 6) & 7, d = col & 63;
                size_t bh = (size_t)(b2 * 8 + hd);
                if (sect == 0)      qb[(bh * 512 + s2) * 64 + d] = val;
                else if (sect == 1) kb[(bh * 512 + s2) * 64 + d] = val;
                else                vb[(bh * 64 + d) * 512 + s2] = val;
            }
        }
    }
}

// ---------------- K4: MFMA attention ----------------
__global__ __launch_bounds__(128) void attn_mfma_kernel(const unsigned short* __restrict__ qb,
                                                        const unsigned short* __restrict__ kb,
                                                        const unsigned short* __restrict__ vb,
                                                        float* __restrict__ o) {
    constexpr int SP = 520;
    __shared__ unsigned short sp[2][16 * SP];
    const int blk = blockIdx.x;
    const int qt = blk & 15;
    const int bh = blk >> 4;
    const int tid = threadIdx.x;
    const int lane = tid & 63, wave = tid >> 6;
    const int fr = lane & 15, fq = lane >> 4;
    const int q0 = qt * 32 + wave * 16;
    const unsigned short* qrow = &qb[((size_t)bh * 512 + q0 + fr) * 64];
    short8 aq0 = *(const short8*)(qrow + fq * 8);
    short8 aq1 = *(const short8*)(qrow + 32 + fq * 8);
    floatx4 sc[32];
#pragma unroll
    for (int t = 0; t < 32; t++) {
        const unsigned short* krow = &kb[((size_t)bh * 512 + t * 16 + fr) * 64];
        short8 bk0 = *(const short8*)(krow + fq * 8);
        short8 bk1 = *(const short8*)(krow + 32 + fq * 8);
        floatx4 a = {};
        a = __builtin_amdgcn_mfma_f32_16x16x32_bf16(aq0, bk0, a, 0, 0, 0);
        a = __builtin_amdgcn_mfma_f32_16x16x32_bf16(aq1, bk1, a, 0, 0, 0);
        sc[t] = a;
    }
    float mr[4], lr[4];
#pragma unroll
    for (int r = 0; r < 4; r++) {
        float m = -1e30f;
#pragma unroll
        for (int t = 0; t < 32; t++) m = fmaxf(m, sc[t][r]);
        for (int ox = 1; ox < 16; ox <<= 1) m = fmaxf(m, __shfl_xor(m, ox));
        mr[r] = m * 0.125f;
    }
#pragma unroll
    for (int r = 0; r < 4; r++) {
        float s = 0.0f;
#pragma unroll
        for (int t = 0; t < 32; t++) {
            float p = expf(sc[t][r] * 0.125f - mr[r]);
            sc[t][r] = p;
            s += p;
        }
        for (int ox = 1; ox < 16; ox <<= 1) s += __shfl_xor(s, ox);
        lr[r] = s;
    }
    unsigned short* spw = sp[wave];
#pragma unroll
    for (int t = 0; t < 32; t++)
#pragma unroll
        for (int r = 0; r < 4; r++)
            spw[(fq * 4 + r) * SP + t * 16 + fr] = f2bf(sc[t][r]);
    __syncthreads();
    floatx4 oa[4] = {};
#pragma unroll
    for (int kt = 0; kt < 16; kt++) {
        short8 ap = *(const short8*)&spw[fr * SP + kt * 32 + fq * 8];
#pragma unroll
        for (int tn = 0; tn < 4; tn++) {
            const unsigned short* vrow = &vb[((size_t)bh * 64 + tn * 16 + fr) * 512 + kt * 32 + fq * 8];
            short8 bv = *(const short8*)vrow;
            oa[tn] = __builtin_amdgcn_mfma_f32_16x16x32_bf16(ap, bv, oa[tn], 0, 0, 0);
        }
    }
    const int b2 = bh >> 3, h2 = bh & 7;
    float inv[4];
#pragma unroll
    for (int r = 0; r < 4; r++) inv[r] = 1.0f / lr[r];
#pragma unroll
    for (int tn = 0; tn < 4; tn++)
#pragma unroll
        for (int r = 0; r < 4; r++) {
            int row = fq * 4 + r;
            int col = tn * 16 + fr;
            o[((size_t)b2 * 512 + q0 + row) * 512 + h2 * 64 + col] = oa[tn][r] * inv[r];
        }
}

// ---------------- K3b: SAGE MFMA GEMM ----------------
__global__ __launch_bounds__(256) void sage_mfma_kernel(const unsigned short* __restrict__ agg_bf,
                                                        const unsigned short* __restrict__ g_bf,
                                                        const float* __restrict__ wl,
                                                        const float* __restrict__ wr,
                                                        const float* __restrict__ bl,
                                                        float* __restrict__ pre) {
    constexpr int LDH = 40;
    __shared__ unsigned short As[128 * LDH];
    __shared__ unsigned short Ws[128 * LDH];
    const int bm = blockIdx.y * 128, bn = blockIdx.x * 128;
    const int tid = threadIdx.x;
    const int lane = tid & 63, wave = tid >> 6;
    const int wm = (wave & 1) * 64, wn = (wave >> 1) * 64;
    const int fr = lane & 15, fq = lane >> 4;
    floatx4 acc[4][4] = {};
    const int srow = tid >> 1, shalf = (tid & 1) * 16;
    int an = bm + srow; if (an >= NN) an = NN - 1;
    const int outc = bn + srow;
    unsigned short* aS = &As[srow * LDH + shalf];
    unsigned short* wS = &Ws[srow * LDH + shalf];
    for (int k0 = 0; k0 < 512; k0 += 32) {
        int kg = k0 + shalf;
        const unsigned short* asrc = (kg < 256) ? &agg_bf[(size_t)an * 256 + kg]
                                                : &g_bf[(size_t)an * 256 + (kg - 256)];
        const float* bsrc = (kg < 256) ? &wl[(size_t)outc * 256 + kg]
                                       : &wr[(size_t)outc * 256 + (kg - 256)];
        ushort8 alo = *(const ushort8*)asrc;
        ushort8 ahi = *(const ushort8*)(asrc + 8);
        floatx4 w0 = *(const floatx4*)(bsrc);
        floatx4 w1 = *(const floatx4*)(bsrc + 4);
        floatx4 w2 = *(const floatx4*)(bsrc + 8);
        floatx4 w3 = *(const floatx4*)(bsrc + 12);
        __syncthreads();
        *(ushort8*)(aS)     = alo;
        *(ushort8*)(aS + 8) = ahi;
        *(ushort8*)(wS)     = pack8(w0, w1);
        *(ushort8*)(wS + 8) = pack8(w2, w3);
        __syncthreads();
        short8 af[4], bfr[4];
#pragma unroll
        for (int i = 0; i < 4; i++) {
            af[i]  = *(const short8*)&As[(wm + i * 16 + fr) * LDH + fq * 8];
            bfr[i] = *(const short8*)&Ws[(wn + i * 16 + fr) * LDH + fq * 8];
        }
#pragma unroll
        for (int mi = 0; mi < 4; mi++)
#pragma unroll
            for (int ni = 0; ni < 4; ni++)
                acc[mi][ni] = __builtin_amdgcn_mfma_f32_16x16x32_bf16(af[mi], bfr[ni], acc[mi][ni], 0, 0, 0);
    }
#pragma unroll
    for (int mi = 0; mi < 4; mi++) {
#pragma unroll
        for (int r = 0; r < 4; r++) {
            int row = bm + wm + mi * 16 + fq * 4 + r;
            if (row < NN) {
#pragma unroll
                for (int ni = 0; ni < 4; ni++) {
                    int col = bn + wn + ni * 16 + fr;
                    pre[(size_t)row * 256 + col] = acc[mi][ni][r] + bl[col];
                }
            }
        }
    }
}

// ---------------- K3c: residual + LN(256) + ReLU ----------------
__global__ __launch_bounds__(256) void ln_relu_kernel(const float* __restrict__ pre,
                                                      unsigned short* __restrict__ g_bf,
                                                      const float* __restrict__ gnw,
                                                      const float* __restrict__ gnb) {
    int n = blockIdx.x, tid = threadIdx.x;
    float res = ubf(g_bf[(size_t)n * 256 + tid]);
    float v = pre[(size_t)n * 256 + tid] + res;
    __shared__ float p1[4], p2[4];
    float s1 = waveRed(v);
    float s2 = waveRed(v * v);
    if ((tid & 63) == 0) { p1[tid >> 6] = s1; p2[tid >> 6] = s2; }
    __syncthreads();
    float S1 = p1[0] + p1[1] + p1[2] + p1[3];
    float S2 = p2[0] + p2[1] + p2[2] + p2[3];
    float mu = S1 / 256.0f, var = S2 / 256.0f - mu * mu;
    float rs = rsqrtf(fmaxf(var, 0.0f) + 1e-5f);
    float r = (v - mu) * rs * gnw[tid] + gnb[tid];
    g_bf[(size_t)n * 256 + tid] = f2bf(fmaxf(r, 0.0f));
}

// ---------------- K5: masked mean pool over S ----------------
__global__ __launch_bounds__(256) void logpool_kernel(const float* __restrict__ hf, float* __restrict__ lp) {
    int idx = blockIdx.x * 256 + threadIdx.x;
    int b = idx >> 9, d = idx & 511;
    float s = 0.0f;
    for (int t = 0; t < 512; t++) s += hf[(size_t)(b * 512 + t) * 512 + d];
    lp[idx] = s * (1.0f / 512.0f);
}

// ---------------- K6a: node clip + shared LN + per-type affine ----------------
__global__ __launch_bounds__(256) void node_ln_kernel(const float* __restrict__ x,
                                                      const int* __restrict__ ntype,
                                                      const float* __restrict__ glnw,
                                                      const float* __restrict__ glnb,
                                                      unsigned short* __restrict__ xab) {
    int tid = threadIdx.x;
    int n = blockIdx.x * 4 + (tid >> 6);
    int lane = tid & 63;
    if (n >= NN) return;
    float v = x[(size_t)n * 64 + lane];
    v = fminf(10.0f, fmaxf(-10.0f, v));
    float s1 = waveRed(v);        s1 = __shfl(s1, 0);
    float s2 = waveRed(v * v);    s2 = __shfl(s2, 0);
    float mu = s1 / 64.0f, var = s2 / 64.0f - mu * mu;
    float rs = rsqrtf(fmaxf(var, 0.0f) + 1e-5f);
    int t = ntype[n];
    float r = (v - mu) * rs * glnw[t * 64 + lane] + glnb[t * 64 + lane];
    xab[(size_t)n * 64 + lane] = f2bf(r);
}

// ---------------- K6b: bucket nodes by type ----------------
__global__ __launch_bounds__(256) void bucket_kernel(const int* __restrict__ ntype,
                                                     int* __restrict__ tcur,
                                                     int* __restrict__ perm) {
    __shared__ int lcnt[3], lbase[3];
    int tid = threadIdx.x;
    int n = blockIdx.x * 256 + tid;
    if (tid < 3) lcnt[tid] = 0;
    __syncthreads();
    int t = 0, lpos = 0;
    bool act = (n < NN);
    if (act) { t = ntype[n]; lpos = atomicAdd(&lcnt[t], 1); }
    __syncthreads();
    if (tid < 3) lbase[tid] = atomicAdd(&tcur[tid], lcnt[tid]);
    __syncthreads();
    if (act) perm[t * NPAD + lbase[t] + lpos] = n;
}

// ---------------- K6c: per-type MFMA GEMM ----------------
__global__ __launch_bounds__(256) void type_gemm_kernel(const unsigned short* __restrict__ xab,
                                                        const int* __restrict__ perm,
                                                        const int* __restrict__ cnts,
                                                        const float* __restrict__ gw,
                                                        const float* __restrict__ gb,
                                                        const float* __restrict__ temb,
                                                        unsigned short* __restrict__ g_bf) {
    constexpr int LDH = 40;
    __shared__ unsigned short As[128 * LDH];
    __shared__ unsigned short Ws[128 * LDH];
    const int t = blockIdx.z;
    const int cnt = cnts[t];
    const int bm = blockIdx.y * 128, bn = blockIdx.x * 128;
    if (bm >= cnt) return;
    const int tid = threadIdx.x;
    const int lane = tid & 63, wave = tid >> 6;
    const int wm = (wave & 1) * 64, wn = (wave >> 1) * 64;
    const int fr = lane & 15, fq = lane >> 4;
    floatx4 acc[4][4] = {};
    const int srow = tid >> 1, shalf = (tid & 1) * 16;
    int gr = bm + srow; if (gr >= cnt) gr = cnt - 1;
    const int node = perm[t * NPAD + gr];
    const int outc = bn + srow;
    unsigned short* aS = &As[srow * LDH + shalf];
    unsigned short* wS = &Ws[srow * LDH + shalf];
#pragma unroll
    for (int k0 = 0; k0 < 64; k0 += 32) {
        const unsigned short* asrc = &xab[(size_t)node * 64 + k0 + shalf];
        const float* bsrc = &gw[((size_t)t * 256 + outc) * 64 + k0 + shalf];
        ushort8 alo = *(const ushort8*)asrc;
        ushort8 ahi = *(const ushort8*)(asrc + 8);
        floatx4 w0 = *(const floatx4*)(bsrc);
        floatx4 w1 = *(const floatx4*)(bsrc + 4);
        floatx4 w2 = *(const floatx4*)(bsrc + 8);
        floatx4 w3 = *(const floatx4*)(bsrc + 12);
        __syncthreads();
        *(ushort8*)(aS)     = alo;
        *(ushort8*)(aS + 8) = ahi;
        *(ushort8*)(wS)     = pack8(w0, w1);
        *(ushort8*)(wS + 8) = pack8(w2, w3);
        __syncthreads();
        short8 af[4], bfr[4];
#pragma unroll
        for (int i = 0; i < 4; i++) {
            af[i]  = *(const short8*)&As[(wm + i * 16 + fr) * LDH + fq * 8];
            bfr[i] = *(const short8*)&Ws[(wn + i * 16 + fr) * LDH + fq * 8];
        }
#pragma unroll
        for (int mi = 0; mi < 4; mi++)
#pragma unroll
            for (int ni = 0; ni < 4; ni++)
                acc[mi][ni] = __builtin_amdgcn_mfma_f32_16x16x32_bf16(af[mi], bfr[ni], acc[mi][ni], 0, 0, 0);
    }
#pragma unroll
    for (int mi = 0; mi < 4; mi++) {
#pragma unroll
        for (int r = 0; r < 4; r++) {
            int row = bm + wm + mi * 16 + fq * 4 + r;
            if (row < cnt) {
                int nd = perm[t * NPAD + row];
#pragma unroll
                for (int ni = 0; ni < 4; ni++) {
                    int col = bn + wn + ni * 16 + fr;
                    g_bf[(size_t)nd * 256 + col] =
                        f2bf(acc[mi][ni][r] + gb[t * 256 + col] + temb[t * 256 + col]);
                }
            }
        }
    }
}

// ---------------- CSR build: hist + 3-phase parallel scan + fill ----------------
__global__ __launch_bounds__(256) void hist_kernel(const int* __restrict__ dst, int* __restrict__ deg) {
    int e = blockIdx.x * 256 + threadIdx.x;
    if (e < EE) atomicAdd(&deg[dst[e]], 1);
}

// phase 1: per-block exclusive scan into row_start (local), block sums -> bsum. 196 blocks.
__global__ __launch_bounds__(256) void scan1_kernel(const int* __restrict__ deg,
                                                    int* __restrict__ row_start,
                                                    int* __restrict__ bsum) {
    __shared__ int buf[256];
    int tid = threadIdx.x;
    int i = blockIdx.x * 256 + tid;
    int v = (i < NN) ? deg[i] : 0;
    buf[tid] = v;
    __syncthreads();
    for (int off = 1; off < 256; off <<= 1) {
        int t = (tid >= off) ? buf[tid - off] : 0;
        __syncthreads();
        buf[tid] += t;
        __syncthreads();
    }
    if (i < NN) row_start[i] = buf[tid] - v;   // exclusive local prefix
    if (tid == 255) bsum[blockIdx.x] = buf[255];
}

// phase 2: single block scans the 196 block sums -> boff (exclusive)
__global__ __launch_bounds__(256) void scan2_kernel(const int* __restrict__ bsum,
                                                    int* __restrict__ boff) {
    __shared__ int buf[256];
    int tid = threadIdx.x;
    int v = (tid < NB) ? bsum[tid] : 0;
    buf[tid] = v;
    __syncthreads();
    for (int off = 1; off < 256; off <<= 1) {
        int t = (tid >= off) ? buf[tid - off] : 0;
        __syncthreads();
        buf[tid] += t;
        __syncthreads();
    }
    boff[tid] = buf[tid] - v;
}

// phase 3: add block offsets, mirror into cursor, cap row_start[NN]. 196 blocks.
__global__ __launch_bounds__(256) void scan3_kernel(const int* __restrict__ boff,
                                                    int* __restrict__ row_start,
                                                    int* __restrict__ cursor) {
    int i = blockIdx.x * 256 + threadIdx.x;
    if (i < NN) {
        int r = row_start[i] + boff[blockIdx.x];
        row_start[i] = r;
        cursor[i] = r;
    }
    if (i == 0) row_start[NN] = EE;
}

__global__ __launch_bounds__(256) void fill_kernel(const int* __restrict__ src,
                                                   const int* __restrict__ dst,
                                                   int* __restrict__ cursor,
                                                   int* __restrict__ csr_src) {
    int e = blockIdx.x * 256 + threadIdx.x;
    if (e < EE) {
        int pos = atomicAdd(&cursor[dst[e]], 1);
        csr_src[pos] = src[e];
    }
}

// ---------------- K8: gather-mean ----------------
__global__ __launch_bounds__(256) void gather_mean_kernel(const unsigned int* __restrict__ g32,
                                                          const int* __restrict__ csr_src,
                                                          const int* __restrict__ row_start,
                                                          unsigned int* __restrict__ agg32) {
    int tid = threadIdx.x;
    int n = blockIdx.x * 2 + (tid >> 7);
    int c = tid & 127;
    int beg = row_start[n], end = row_start[n + 1];
    float a0 = 0, a1 = 0, a2 = 0, a3 = 0;
    float b0 = 0, b1 = 0, b2 = 0, b3 = 0;
    int i = beg;
    for (; i + 4 <= end; i += 4) {
        int s0 = csr_src[i], s1 = csr_src[i + 1], s2 = csr_src[i + 2], s3 = csr_src[i + 3];
        unsigned int u0 = g32[(size_t)s0 * 128 + c];
        unsigned int u1 = g32[(size_t)s1 * 128 + c];
        unsigned int u2 = g32[(size_t)s2 * 128 + c];
        unsigned int u3 = g32[(size_t)s3 * 128 + c];
        a0 += ubf(u0 & 0xffff); b0 += ubf(u0 >> 16);
        a1 += ubf(u1 & 0xffff); b1 += ubf(u1 >> 16);
        a2 += ubf(u2 & 0xffff); b2 += ubf(u2 >> 16);
        a3 += ubf(u3 & 0xffff); b3 += ubf(u3 >> 16);
    }
    for (; i < end; i++) {
        int s = csr_src[i];
        unsigned int u = g32[(size_t)s * 128 + c];
        a0 += ubf(u & 0xffff); b0 += ubf(u >> 16);
    }
    float den = (end > beg) ? (float)(end - beg) : 1.0f;
    float m0 = ((a0 + a1) + (a2 + a3)) / den;
    float m1 = ((b0 + b1) + (b2 + b3)) / den;
    agg32[(size_t)n * 128 + c] = (unsigned int)f2bf(m0) | ((unsigned int)f2bf(m1) << 16);
}

// ---------------- K11: column mean over N nodes ----------------
__global__ __launch_bounds__(256) void gpool_kernel(const unsigned short* __restrict__ g_bf,
                                                    float* __restrict__ psum) {
    int tid = threadIdx.x, blk = blockIdx.x;
    float acc = 0.0f;
    for (int n = blk; n < NN; n += 256) acc += ubf(g_bf[(size_t)n * 256 + tid]);
    atomicAdd(&psum[tid], acc);
}

// ---------------- K12: fusion linear + LN + ReLU -> f32 out ----------------
__global__ __launch_bounds__(256) void fusion_kernel(const float* __restrict__ lp,
                                                     const float* __restrict__ psum,
                                                     const float* __restrict__ fw,
                                                     const float* __restrict__ fb,
                                                     const float* __restrict__ flnw,
                                                     const float* __restrict__ flnb,
                                                     float* __restrict__ out) {
    int b = blockIdx.x, tid = threadIdx.x;
    __shared__ float fin[768], fo[768];
    __shared__ float p1[4], p2[4];
    for (int i = tid; i < 512; i += 256) fin[i] = lp[b * 512 + i];
    if (tid < 256) fin[512 + tid] = psum[tid] * (1.0f / 50000.0f);
    __syncthreads();
    for (int j = tid; j < 768; j += 256) {
        float acc = fb[j];
        const float4* w4 = (const float4*)(fw + (size_t)j * 768);
#pragma unroll 4
        for (int i4 = 0; i4 < 192; i4++) {
            float4 u = w4[i4];
            acc += fin[4 * i4 + 0] * u.x + fin[4 * i4 + 1] * u.y
                 + fin[4 * i4 + 2] * u.z + fin[4 * i4 + 3] * u.w;
        }
        fo[j] = acc;
    }
    __syncthreads();
    float s1 = 0.0f, s2 = 0.0f;
    for (int j = tid; j < 768; j += 256) { float vv = fo[j]; s1 += vv; s2 += vv * vv; }
    s1 = waveRed(s1); s2 = waveRed(s2);
    if ((tid & 63) == 0) { p1[tid >> 6] = s1; p2[tid >> 6] = s2; }
    __syncthreads();
    float S1 = p1[0] + p1[1] + p1[2] + p1[3];
    float S2 = p2[0] + p2[1] + p2[2] + p2[3];
    float mu = S1 / 768.0f, var = S2 / 768.0f - mu * mu;
    float rs = rsqrtf(fmaxf(var, 0.0f) + 1e-5f);
    for (int j = tid; j < 768; j += 256) {
        float r = (fo[j] - mu) * rs * flnw[j] + flnb[j];
        out[b * 768 + j] = fmaxf(r, 0.0f);
    }
}

extern "C" void kernel_launch(void* const* d_in, const int* in_sizes, int n_in,
                              void* d_out, int out_size, void* d_ws, size_t ws_size,
                              hipStream_t stream) {
    (void)in_sizes; (void)n_in; (void)out_size; (void)ws_size;
    const float* tok_emb = (const float*)d_in[0];
    const float* qkv_w   = (const float*)d_in[1];
    const float* qkv_b   = (const float*)d_in[2];
    const float* out_w   = (const float*)d_in[3];
    const float* out_b   = (const float*)d_in[4];
    const float* ln1_w   = (const float*)d_in[5];
    const float* ln1_b   = (const float*)d_in[6];
    const float* ln2_w   = (const float*)d_in[7];
    const float* ln2_b   = (const float*)d_in[8];
    const float* ff1_w   = (const float*)d_in[9];
    const float* ff1_b   = (const float*)d_in[10];
    const float* ff2_w   = (const float*)d_in[11];
    const float* ff2_b   = (const float*)d_in[12];
    const float* fln_w   = (const float*)d_in[13];
    const float* fln_b   = (const float*)d_in[14];
    const float* x       = (const float*)d_in[15];
    const float* gln_w   = (const float*)d_in[16];
    const float* gln_b   = (const float*)d_in[17];
    const float* gw      = (const float*)d_in[18];
    const float* gb      = (const float*)d_in[19];
    const float* temb    = (const float*)d_in[20];
    const float* sage_wl = (const float*)d_in[21];
    const float* sage_bl = (const float*)d_in[22];
    const float* sage_wr = (const float*)d_in[23];
    const float* gnorm_w = (const float*)d_in[24];
    const float* gnorm_b = (const float*)d_in[25];
    const float* fusion_w   = (const float*)d_in[26];
    const float* fusion_b   = (const float*)d_in[27];
    const float* fusion_lnw = (const float*)d_in[28];
    const float* fusion_lnb = (const float*)d_in[29];
    const int* input_ids  = (const int*)d_in[30];
    // d_in[31] = attention_mask: all-true, unused
    const int* edge_index = (const int*)d_in[32];
    const int* node_type  = (const int*)d_in[33];
    const int* e_src = edge_index;
    const int* e_dst = edge_index + EE;

    // workspace layout (float units)
    float* ws  = (float*)d_ws;
    float* h   = ws;                      // 2,097,152
    float* y   = ws + 2097152;            // 2,097,152
    float* ff  = ws + 4194304;            // 8,388,608 floats
    unsigned short* xab = (unsigned short*)ws;            // graph phase (aliases h/y)
    int* perm  = (int*)(ws + 1601536);
    int* tcur  = (int*)(ws + 1751680);
    float* pre = ws;                      // NPAD*256 floats (sage phase)
    unsigned short* q_bf = (unsigned short*)(ws + 12812288);
    unsigned short* k_bf = q_bf + 2097152;
    unsigned short* v_bf = q_bf + 4194304;
    unsigned short* g_bf   = (unsigned short*)(ws + 12812288);
    unsigned short* agg_bf = (unsigned short*)(ws + 19218432);
    float* lp   = ws + 25624576;          // 4096
    float* psum = ws + 25628672;          // 256
    int* ibase     = (int*)(ws + 25628928);
    int* deg_i     = ibase;               // 50,000
    int* row_start = ibase + 50000;       // 50,001
    int* cursor    = ibase + 100001;      // 50,000
    int* csr_src   = ibase + 150001;      // 800,000
    int* bsum      = ibase + 950001;      // 256
    int* boff      = ibase + 950257;      // 256
    // total: 26,579,441 floats = 106.3 MB

    // ---- transformer ----
    embed_kernel<<<T, 256, 0, stream>>>(tok_emb, input_ids, h);
    for (int l = 0; l < L; l++) {
        ln512_kernel<<<T, 256, 0, stream>>>(h, ln1_w + l * D, ln1_b + l * D, y);
        qkv_gemm_kernel<<<dim3(12, 32), 256, 0, stream>>>(
            y, qkv_w + (size_t)l * 3 * D * D, qkv_b + (size_t)l * 3 * D, q_bf, k_bf, v_bf);
        attn_mfma_kernel<<<B * NH * (S / 32), 128, 0, stream>>>(q_bf, k_bf, v_bf, y);
        mfma_gemm_kernel<0, true><<<dim3(D / 128, T / 128), 256, 0, stream>>>(
            y, out_w + (size_t)l * D * D, out_b + (size_t)l * D, h, h, T, D, D);
        ln512_kernel<<<T, 256, 0, stream>>>(h, ln2_w + l * D, ln2_b + l * D, y);
        mfma_gemm_kernel<1, false><<<dim3(FF / 128, T / 128), 256, 0, stream>>>(
            y, ff1_w + (size_t)l * FF * D, ff1_b + (size_t)l * FF, nullptr, ff, T, FF, D);
        mfma_gemm_kernel<0, true><<<dim3(D / 128, T / 128), 256, 0, stream>>>(
            ff, ff2_w + (size_t)l * D * FF, ff2_b + (size_t)l * D, h, h, T, D, FF);
    }
    ln512_kernel<<<T, 256, 0, stream>>>(h, fln_w, fln_b, y);
    logpool_kernel<<<(B * D) / 256, 256, 0, stream>>>(y, lp);

    // ---- graph: node encode ----
    node_ln_kernel<<<(NN + 3) / 4, 256, 0, stream>>>(x, node_type, gln_w, gln_b, xab);
    hipMemsetAsync(tcur, 0, 3 * sizeof(int), stream);
    bucket_kernel<<<(NN + 255) / 256, 256, 0, stream>>>(node_type, tcur, perm);
    type_gemm_kernel<<<dim3(2, NPAD / 128, 3), 256, 0, stream>>>(xab, perm, tcur, gw, gb, temb, g_bf);

    // ---- CSR build (parallel scan) ----
    hipMemsetAsync(deg_i, 0, NN * sizeof(int), stream);
    hist_kernel<<<(EE + 255) / 256, 256, 0, stream>>>(e_dst, deg_i);
    scan1_kernel<<<NB, 256, 0, stream>>>(deg_i, row_start, bsum);
    scan2_kernel<<<1, 256, 0, stream>>>(bsum, boff);
    scan3_kernel<<<NB, 256, 0, stream>>>(boff, row_start, cursor);
    fill_kernel<<<(EE + 255) / 256, 256, 0, stream>>>(e_src, e_dst, cursor, csr_src);

    // ---- 2 SAGE layers ----
    for (int l = 0; l < 2; l++) {
        gather_mean_kernel<<<NN / 2, 256, 0, stream>>>((const unsigned int*)g_bf, csr_src, row_start,
                                                       (unsigned int*)agg_bf);
        sage_mfma_kernel<<<dim3(2, NPAD / 128), 256, 0, stream>>>(agg_bf, g_bf,
            sage_wl + (size_t)l * HG * HG, sage_wr + (size_t)l * HG * HG, sage_bl + (size_t)l * HG, pre);
        ln_relu_kernel<<<NN, 256, 0, stream>>>(pre, g_bf,
            gnorm_w + (size_t)l * HG, gnorm_b + (size_t)l * HG);
    }
    hipMemsetAsync(psum, 0, HG * sizeof(float), stream);
    gpool_kernel<<<256, 256, 0, stream>>>(g_bf, psum);
    fusion_kernel<<<B, 256, 0, stream>>>(lp, psum, fusion_w, fusion_b, fusion_lnw, fusion_lnb,
                                         (float*)d_out);
}